// Round 4
// baseline (3681.455 us; speedup 1.0000x reference)
//
#include <hip/hip_runtime.h>
#include <hip/hip_bf16.h>

#define B_ 32
#define DIM_ 384
#define R_ 28
#define N_ 784
#define H_ 8
#define KD_ 32
#define D_ 128
#define DH_ 1024
#define SCALE_ 0.17677669529663687f
#define NARR 26

typedef unsigned short u16;
typedef __attribute__((ext_vector_type(4))) float f32x4;
typedef __attribute__((ext_vector_type(8))) short s16x8;

__device__ __forceinline__ float b2f(u16 b) {
  union { unsigned int u; float f; } v; v.u = ((unsigned int)b) << 16; return v.f;
}
__device__ __forceinline__ u16 f2b(float f) {
  union { float f; unsigned int u; } v; v.f = f;
  unsigned int r = v.u + 0x7fffu + ((v.u >> 16) & 1u);
  return (u16)(r >> 16);
}

// ---------- dtype probe: bf16 data has exp field in a narrow band ----------
__global__ void k_detect(const u16* __restrict__ x, int* __restrict__ flag) {
  __shared__ int cnt;
  if (threadIdx.x == 0) cnt = 0;
  __syncthreads();
  int c = 0;
  for (int i = threadIdx.x; i < 8192; i += 256) {
    int e = (x[i] >> 7) & 0xFF;
    if (e < 64 || e > 160) ++c;
  }
  atomicAdd(&cnt, c);
  __syncthreads();
  if (threadIdx.x == 0) *flag = (cnt > 256) ? 1 : 0;  // 1 => inputs are f32
}

struct NormTab {
  const void* src[NARR];
  u16* dst[NARR];
  int n[NARR];
};

__global__ __launch_bounds__(256) void k_normalize(NormTab tab, const int* __restrict__ flag) {
  int a = blockIdx.y;
  int n = tab.n[a];
  int f = *flag;
  u16* dst = tab.dst[a];
  if (f) {
    const float* s = (const float*)tab.src[a];
    for (int i = blockIdx.x * 256 + threadIdx.x; i < n; i += gridDim.x * 256)
      dst[i] = f2b(s[i]);
  } else {
    const u16* s = (const u16*)tab.src[a];
    for (int i = blockIdx.x * 256 + threadIdx.x; i < n; i += gridDim.x * 256)
      dst[i] = s[i];
  }
}

// 4 waves, block tile 64x64, wave tile 32x32 (2x2 of 16x16x32 bf16 MFMA).
// Both LDS operands stored [out-index][k] with k contiguous (32 bf16/row).
__device__ __forceinline__ void mfma_tile(const u16 (*A)[32], const u16 (*B)[32],
                                          int wm, int wn, int l16, int quad,
                                          f32x4 acc[2][2]) {
  s16x8 a0 = *(const s16x8*)&A[wm * 32 + l16][quad * 8];
  s16x8 a1 = *(const s16x8*)&A[wm * 32 + 16 + l16][quad * 8];
  s16x8 b0 = *(const s16x8*)&B[wn * 32 + l16][quad * 8];
  s16x8 b1 = *(const s16x8*)&B[wn * 32 + 16 + l16][quad * 8];
  acc[0][0] = __builtin_amdgcn_mfma_f32_16x16x32_bf16(a0, b0, acc[0][0], 0, 0, 0);
  acc[0][1] = __builtin_amdgcn_mfma_f32_16x16x32_bf16(a0, b1, acc[0][1], 0, 0, 0);
  acc[1][0] = __builtin_amdgcn_mfma_f32_16x16x32_bf16(a1, b0, acc[1][0], 0, 0, 0);
  acc[1][1] = __builtin_amdgcn_mfma_f32_16x16x32_bf16(a1, b1, acc[1][1], 0, 0, 0);
}

// ---------------- K0: transpose x [b][c][n] -> xT [bl][n][c] ----------------
__global__ __launch_bounds__(256) void k_transpose(const u16* __restrict__ x,
                                                   u16* __restrict__ xT, int b0) {
  __shared__ u16 tile[64][65];
  int nt = blockIdx.x, ct = blockIdx.y, bl = blockIdx.z;
  int t = threadIdx.x;
  int n0 = nt * 64, c0 = ct * 64;
  const u16* xb = x + (size_t)(b0 + bl) * DIM_ * N_;
  int nl = t & 63, cg = t >> 6;
  for (int i = 0; i < 16; ++i) {
    int cl = cg * 16 + i;
    int n = n0 + nl;
    u16 val = 0;
    if (n < N_) val = xb[(size_t)(c0 + cl) * N_ + n];
    tile[cl][nl] = val;
  }
  __syncthreads();
  u16* xTb = xT + (size_t)bl * N_ * DIM_;
  int cl = t & 63, ng = t >> 6;
  for (int i = 0; i < 16; ++i) {
    int n2 = n0 + ng * 16 + i;
    if (n2 < N_) xTb[(size_t)n2 * DIM_ + (c0 + cl)] = tile[cl][ng * 16 + i];
  }
}

// ---------------- K1: fused QKV projection + BN affine ----------------
__global__ __launch_bounds__(256) void k_proj(
    const u16* __restrict__ xT,
    const u16* __restrict__ Wq, const u16* __restrict__ bq, const u16* __restrict__ sq, const u16* __restrict__ tq,
    const u16* __restrict__ Wk, const u16* __restrict__ bk, const u16* __restrict__ sk, const u16* __restrict__ tk,
    const u16* __restrict__ Wv, const u16* __restrict__ bv, const u16* __restrict__ sv, const u16* __restrict__ tv,
    u16* __restrict__ qb, u16* __restrict__ kb, u16* __restrict__ vb) {
  __shared__ __align__(16) u16 Als[64][32];
  __shared__ __align__(16) u16 Bls[64][32];
  int nt = blockIdx.x, mt = blockIdx.y, bl = blockIdx.z;
  int t = threadIdx.x;
  int oc0 = mt * 64;
  const u16 *Wsrc, *bsrc, *ssrc, *tsrc; int obase;
  if (oc0 < 256)      { Wsrc = Wq; bsrc = bq; ssrc = sq; tsrc = tq; obase = oc0; }
  else if (oc0 < 512) { Wsrc = Wk; bsrc = bk; ssrc = sk; tsrc = tk; obase = oc0 - 256; }
  else                { Wsrc = Wv; bsrc = bv; ssrc = sv; tsrc = tv; obase = oc0 - 512; }

  int lane = t & 63, wid = t >> 6;
  int wm = wid & 1, wn = wid >> 1;
  int l16 = lane & 15, quad = lane >> 4;
  int srow = t >> 2, skoff = (t & 3) * 8;

  f32x4 acc[2][2] = {};
  const u16* xTb = xT + (size_t)bl * N_ * DIM_;

  for (int kc = 0; kc < DIM_ / 32; ++kc) {
    int k0 = kc * 32;
    *(s16x8*)&Als[srow][skoff] =
        *(const s16x8*)&Wsrc[(size_t)(obase + srow) * DIM_ + k0 + skoff];
    int n = nt * 64 + srow;
    s16x8 bvv = {};
    if (n < N_) bvv = *(const s16x8*)&xTb[(size_t)n * DIM_ + k0 + skoff];
    *(s16x8*)&Bls[srow][skoff] = bvv;
    __syncthreads();
    mfma_tile(Als, Bls, wm, wn, l16, quad, acc);
    __syncthreads();
  }
  for (int mi = 0; mi < 2; ++mi)
    for (int ni = 0; ni < 2; ++ni)
      for (int r = 0; r < 4; ++r) {
        int row = wm * 32 + mi * 16 + quad * 4 + r;
        int col = nt * 64 + wn * 32 + ni * 16 + l16;
        if (col >= N_) continue;
        int oc = oc0 + row;
        int ol = obase + row;
        float val = acc[mi][ni][r];
        val = (val + b2f(bsrc[ol])) * b2f(ssrc[ol]) + b2f(tsrc[ol]);
        u16 o = f2b(val);
        if (oc < 256) {
          int h = oc >> 5, c = oc & 31;
          qb[(((size_t)bl * H_ + h) * N_ + col) * KD_ + c] = o;
        } else if (oc < 512) {
          int oc2 = oc - 256; int h = oc2 >> 5, c = oc2 & 31;
          kb[(((size_t)bl * H_ + h) * N_ + col) * KD_ + c] = o;
        } else {
          int ch = oc - 512;
          vb[((size_t)bl * DH_ + ch) * N_ + col] = o;
        }
      }
}

// ---------------- K2: depthwise 3x3 conv + affine; vl stored [bl][n][ch] ----------------
__global__ __launch_bounds__(256) void k_dwconv(
    const u16* __restrict__ vb, const u16* __restrict__ Wvl,
    const u16* __restrict__ bvl, const u16* __restrict__ svl, const u16* __restrict__ tvl,
    u16* __restrict__ vlb) {
  int y = blockIdx.x, bl = blockIdx.y;
  int t = threadIdx.x;
  for (int pass = 0; pass < 4; ++pass) {
    int ch = pass * 256 + t;
    float w[9];
    for (int i = 0; i < 9; ++i) w[i] = b2f(Wvl[ch * 9 + i]);
    float bias = b2f(bvl[ch]), sc = b2f(svl[ch]), sh = b2f(tvl[ch]);
    const u16* vp = vb + ((size_t)bl * DH_ + ch) * N_;
    for (int x = 0; x < R_; ++x) {
      float acc = 0.f;
      for (int dy = -1; dy <= 1; ++dy) {
        int yy = y + dy;
        if (yy < 0 || yy >= R_) continue;
        for (int dx = -1; dx <= 1; ++dx) {
          int xx = x + dx;
          if (xx < 0 || xx >= R_) continue;
          acc += b2f(vp[yy * R_ + xx]) * w[(dy + 1) * 3 + (dx + 1)];
        }
      }
      vlb[((size_t)bl * N_ + y * R_ + x) * DH_ + ch] = f2b((acc + bias) * sc + sh);
    }
  }
}

// ---------------- K3: raw scores (f32) Sf[bl][h][nloc][m] = scale*q.k + ab ----------------
__global__ __launch_bounds__(256) void k_scores(
    const u16* __restrict__ qb, const u16* __restrict__ kb, const u16* __restrict__ ab,
    float* __restrict__ Sf, int n0, int NC, int G) {
  __shared__ float abrow[N_];
  __shared__ float biasT[64][64];
  __shared__ __align__(16) u16 Als[64][32];
  __shared__ __align__(16) u16 Bls[64][32];
  int mt = blockIdx.x, ntl = blockIdx.y, h = blockIdx.z;
  int t = threadIdx.x;
  for (int i = t; i < N_; i += 256) abrow[i] = b2f(ab[h * N_ + i]);
  __syncthreads();
  int jm = t & 63, ig = t >> 6;
  for (int ii = 0; ii < 16; ++ii) {
    int i = ig * 16 + ii;
    int n_g = n0 + ntl * 64 + i;
    int m_g = mt * 64 + jm;
    float bv = 0.f;
    if (n_g < N_ && m_g < N_) {
      int yn = n_g / R_, xn = n_g - yn * R_;
      int ym = m_g / R_, xm = m_g - ym * R_;
      int dy = yn - ym; if (dy < 0) dy = -dy;
      int dx = xn - xm; if (dx < 0) dx = -dx;
      bv = abrow[dy * R_ + dx];
    }
    biasT[i][jm] = bv;
  }
  int lane = t & 63, wid = t >> 6;
  int wm = wid & 1, wn = wid >> 1;
  int l16 = lane & 15, quad = lane >> 4;
  int srow = t >> 2, skoff = (t & 3) * 8;

  for (int bl = 0; bl < G; ++bl) {
    __syncthreads();
    {
      int nloc = ntl * 64 + srow;
      int n_g = n0 + nloc;
      s16x8 av = {};
      if (nloc < NC && n_g < N_)
        av = *(const s16x8*)&qb[(((size_t)bl * H_ + h) * N_ + n_g) * KD_ + skoff];
      *(s16x8*)&Als[srow][skoff] = av;
      int m_g = mt * 64 + srow;
      s16x8 bv2 = {};
      if (m_g < N_)
        bv2 = *(const s16x8*)&kb[(((size_t)bl * H_ + h) * N_ + m_g) * KD_ + skoff];
      *(s16x8*)&Bls[srow][skoff] = bv2;
    }
    __syncthreads();
    f32x4 acc[2][2] = {};
    mfma_tile(Als, Bls, wm, wn, l16, quad, acc);
    for (int mi = 0; mi < 2; ++mi)
      for (int ni = 0; ni < 2; ++ni)
        for (int r = 0; r < 4; ++r) {
          int row = wm * 32 + mi * 16 + quad * 4 + r;
          int col = wn * 32 + ni * 16 + l16;
          int nloc = ntl * 64 + row;
          int m_g = mt * 64 + col;
          if (nloc < NC && (n0 + nloc) < N_ && m_g < N_) {
            Sf[(((size_t)bl * H_ + h) * NC + nloc) * N_ + m_g] =
                acc[mi][ni][r] * SCALE_ + biasT[row][col];
          }
        }
  }
}

// ---------------- K4: th1-mix + softmax + th2-mix; f32 in, bf16 probs out ----------------
__global__ __launch_bounds__(256) void k_softmax(
    const float* __restrict__ Sf, u16* __restrict__ P,
    const u16* __restrict__ th1w, const u16* __restrict__ th1b,
    const u16* __restrict__ th2w, const u16* __restrict__ th2b, int NC) {
  __shared__ float sm[H_][N_];
  __shared__ float w1[64], bb1[8], w2[64], bb2[8], linv[8];
  int ncl = blockIdx.x, bl = blockIdx.y;
  int t = threadIdx.x;
  if (t < 64) { w1[t] = b2f(th1w[t]); w2[t] = b2f(th2w[t]); }
  if (t < 8)  { bb1[t] = b2f(th1b[t]); bb2[t] = b2f(th2b[t]); }
  __syncthreads();
  size_t base = ((size_t)bl * H_ * NC + ncl) * N_;
  size_t hstr = (size_t)NC * N_;
  for (int m = t; m < N_; m += 256) {
    float s[8];
    for (int h = 0; h < 8; ++h) s[h] = Sf[base + h * hstr + m];
    for (int g = 0; g < 8; ++g) {
      float a = bb1[g];
      for (int h = 0; h < 8; ++h) a += w1[g * 8 + h] * s[h];
      sm[g][m] = a;
    }
  }
  __syncthreads();
  int lane = t & 63, wid = t >> 6;
  for (int gi = 0; gi < 2; ++gi) {
    int g = wid + gi * 4;
    float mx = -1e30f;
    for (int m = lane; m < N_; m += 64) mx = fmaxf(mx, sm[g][m]);
    for (int off = 32; off >= 1; off >>= 1) mx = fmaxf(mx, __shfl_xor(mx, off));
    float sum = 0.f;
    for (int m = lane; m < N_; m += 64) {
      float e = __expf(sm[g][m] - mx);
      sm[g][m] = e;
      sum += e;
    }
    for (int off = 32; off >= 1; off >>= 1) sum += __shfl_xor(sum, off);
    if (lane == 0) linv[g] = 1.f / sum;
  }
  __syncthreads();
  float li[8];
  for (int g = 0; g < 8; ++g) li[g] = linv[g];
  for (int m = t; m < N_; m += 256) {
    float p[8];
    for (int g = 0; g < 8; ++g) p[g] = sm[g][m] * li[g];
    for (int f = 0; f < 8; ++f) {
      float a = bb2[f];
      for (int g = 0; g < 8; ++g) a += w2[f * 8 + g] * p[g];
      P[base + f * hstr + m] = f2b(a);
    }
  }
}

// ---------------- K5: O'[bl][n][ch] = relu(attn @ V + vl) ----------------
__global__ __launch_bounds__(256) void k_pv(
    const u16* __restrict__ P, const u16* __restrict__ vb, const u16* __restrict__ vlb,
    u16* __restrict__ ob, int n0, int NC) {
  __shared__ __align__(16) u16 Als[64][32];  // V rows (d)
  __shared__ __align__(16) u16 Bls[64][32];  // attn rows (n)
  int ntl = blockIdx.x, dt = blockIdx.y, z = blockIdx.z;
  int bl = z >> 3, f = z & 7;
  int t = threadIdx.x;
  int lane = t & 63, wid = t >> 6;
  int wm = wid & 1, wn = wid >> 1;
  int l16 = lane & 15, quad = lane >> 4;
  int srow = t >> 2, skoff = (t & 3) * 8;

  f32x4 acc[2][2] = {};
  const u16* vsrc = vb + ((size_t)bl * DH_ + f * D_ + dt * 64) * N_;
  const u16* asrc = P + ((size_t)bl * H_ + f) * NC * N_;

  for (int kc = 0; kc < 25; ++kc) {
    int kk = kc * 32 + skoff;
    s16x8 av = {}, bv = {};
    if (kk + 8 <= N_) av = *(const s16x8*)&vsrc[(size_t)srow * N_ + kk];
    int nloc = ntl * 64 + srow;
    if (nloc < NC && kk + 8 <= N_) bv = *(const s16x8*)&asrc[(size_t)nloc * N_ + kk];
    *(s16x8*)&Als[srow][skoff] = av;
    *(s16x8*)&Bls[srow][skoff] = bv;
    __syncthreads();
    mfma_tile(Als, Bls, wm, wn, l16, quad, acc);
    __syncthreads();
  }
  for (int mi = 0; mi < 2; ++mi)
    for (int ni = 0; ni < 2; ++ni) {
      int row = wm * 32 + mi * 16 + quad * 4;  // d local, 4 regs = 4 contiguous d
      int col = wn * 32 + ni * 16 + l16;       // token local
      int nloc = ntl * 64 + col;
      if (nloc >= NC || (n0 + nloc) >= N_) continue;
      int ch = f * D_ + dt * 64 + row;
      size_t addr = ((size_t)bl * N_ + (n0 + nloc)) * DH_ + ch;
      ushort4 vl4 = *(const ushort4*)&vlb[addr];
      float o0 = acc[mi][ni][0] + b2f(vl4.x);
      float o1 = acc[mi][ni][1] + b2f(vl4.y);
      float o2 = acc[mi][ni][2] + b2f(vl4.z);
      float o3 = acc[mi][ni][3] + b2f(vl4.w);
      ushort4 o4;
      o4.x = f2b(o0 > 0.f ? o0 : 0.f);
      o4.y = f2b(o1 > 0.f ? o1 : 0.f);
      o4.z = f2b(o2 > 0.f ? o2 : 0.f);
      o4.w = f2b(o3 > 0.f ? o3 : 0.f);
      *(ushort4*)&ob[addr] = o4;
    }
}

// ---------------- K6: out[b0+bl][oc][n] = affine(Wp @ O' + bp), f32 output ----------------
__global__ __launch_bounds__(256) void k_outproj(
    const u16* __restrict__ ob, const u16* __restrict__ Wp,
    const u16* __restrict__ bp, const u16* __restrict__ sp, const u16* __restrict__ tp,
    float* __restrict__ out, int b0) {
  __shared__ __align__(16) u16 Als[64][32];
  __shared__ __align__(16) u16 Bls[64][32];
  int nt = blockIdx.x, mt = blockIdx.y, bl = blockIdx.z;
  int t = threadIdx.x;
  int lane = t & 63, wid = t >> 6;
  int wm = wid & 1, wn = wid >> 1;
  int l16 = lane & 15, quad = lane >> 4;
  int srow = t >> 2, skoff = (t & 3) * 8;

  f32x4 acc[2][2] = {};
  const u16* obb = ob + (size_t)bl * N_ * DH_;

  for (int kc = 0; kc < DH_ / 32; ++kc) {
    int k0 = kc * 32;
    *(s16x8*)&Als[srow][skoff] =
        *(const s16x8*)&Wp[(size_t)(mt * 64 + srow) * DH_ + k0 + skoff];
    int n = nt * 64 + srow;
    s16x8 bvv = {};
    if (n < N_) bvv = *(const s16x8*)&obb[(size_t)n * DH_ + k0 + skoff];
    *(s16x8*)&Bls[srow][skoff] = bvv;
    __syncthreads();
    mfma_tile(Als, Bls, wm, wn, l16, quad, acc);
    __syncthreads();
  }
  for (int mi = 0; mi < 2; ++mi)
    for (int ni = 0; ni < 2; ++ni)
      for (int r = 0; r < 4; ++r) {
        int oc = mt * 64 + wm * 32 + mi * 16 + quad * 4 + r;
        int n = nt * 64 + wn * 32 + ni * 16 + l16;
        if (n >= N_) continue;
        float val = (acc[mi][ni][r] + b2f(bp[oc])) * b2f(sp[oc]) + b2f(tp[oc]);
        out[((size_t)(b0 + bl) * DIM_ + oc) * N_ + n] = val;  // f32 output
      }
}

extern "C" void kernel_launch(void* const* d_in, const int* in_sizes, int n_in,
                              void* d_out, int out_size, void* d_ws, size_t ws_size,
                              hipStream_t stream) {
  (void)n_in; (void)out_size;
  float* out = (float*)d_out;  // reference output dtype is float32

  char* ws = (char*)d_ws;
  size_t off = 0;
  auto alloc = [&](size_t bytes) -> void* {
    void* p = ws + off;
    off += (bytes + 255) & ~(size_t)255;
    return p;
  };

  // --- fixed region: dtype flag + normalized bf16 copies of the 26 tensor inputs ---
  int* flag = (int*)alloc(256);
  NormTab tab;
  u16* nrm[NARR];
  for (int i = 0; i < NARR; ++i) {
    int n = in_sizes[i];
    nrm[i] = (u16*)alloc((size_t)n * 2);
    tab.src[i] = d_in[i];
    tab.dst[i] = nrm[i];
    tab.n[i] = n;
  }
  size_t fixed = off;

  const u16* xn   = nrm[0];
  const u16* Wq   = nrm[1];
  const u16* bq   = nrm[2];
  const u16* sq   = nrm[3];
  const u16* tq   = nrm[4];
  const u16* Wk   = nrm[5];
  const u16* bk   = nrm[6];
  const u16* sk   = nrm[7];
  const u16* tk   = nrm[8];
  const u16* Wv   = nrm[9];
  const u16* bv   = nrm[10];
  const u16* sv   = nrm[11];
  const u16* tv   = nrm[12];
  const u16* Wvl  = nrm[13];
  const u16* bvl  = nrm[14];
  const u16* svl  = nrm[15];
  const u16* tvl  = nrm[16];
  const u16* th1w = nrm[17];
  const u16* th1b = nrm[18];
  const u16* th2w = nrm[19];
  const u16* th2b = nrm[20];
  const u16* ab   = nrm[21];
  const u16* Wp   = nrm[22];
  const u16* bp   = nrm[23];
  const u16* sp   = nrm[24];
  const u16* tp   = nrm[25];

  // --- pick batch-group size G and n-chunk NC so everything fits ws_size ---
  auto footprint = [fixed](int G, int NC) -> size_t {
    auto al = [](size_t b) { return (b + 255) & ~(size_t)255; };
    size_t a = fixed;
    a += al((size_t)G * H_ * N_ * KD_ * 2);   // qb
    a += al((size_t)G * H_ * N_ * KD_ * 2);   // kb
    a += al((size_t)G * DH_ * N_ * 2);        // vb
    a += al((size_t)G * N_ * DH_ * 2);        // vlb
    a += al((size_t)G * N_ * DH_ * 2);        // obb
    size_t xtb = (size_t)G * N_ * DIM_ * 2;
    size_t sb = (size_t)G * H_ * NC * N_ * 4; // Sf (f32), aliases xT
    a += al(sb > xtb ? sb : xtb);
    a += al((size_t)G * H_ * NC * N_ * 2);    // P (bf16 probs)
    return a;
  };
  const int Gs[6] = {32, 16, 8, 4, 2, 1};
  const int NCs[6] = {784, 392, 196, 112, 56, 28};
  int G = 1, NC = 28;
  bool found = false;
  for (int gi = 0; gi < 6 && !found; ++gi)
    for (int ci = 0; ci < 6 && !found; ++ci)
      if (footprint(Gs[gi], NCs[ci]) <= ws_size) { G = Gs[gi]; NC = NCs[ci]; found = true; }

  u16* qb  = (u16*)alloc((size_t)G * H_ * N_ * KD_ * 2);
  u16* kb  = (u16*)alloc((size_t)G * H_ * N_ * KD_ * 2);
  u16* vb  = (u16*)alloc((size_t)G * DH_ * N_ * 2);
  u16* vlb = (u16*)alloc((size_t)G * N_ * DH_ * 2);
  u16* obb = (u16*)alloc((size_t)G * N_ * DH_ * 2);
  size_t xtb = (size_t)G * N_ * DIM_ * 2;
  size_t sb = (size_t)G * H_ * NC * N_ * 4;
  float* Sf = (float*)alloc(sb > xtb ? sb : xtb);
  u16* xT = (u16*)Sf;  // xT dead before Sf is first written
  u16* P  = (u16*)alloc((size_t)G * H_ * NC * N_ * 2);

  // --- dtype probe + input normalization (runs once per launch) ---
  hipLaunchKernelGGL(k_detect, dim3(1), dim3(256), 0, stream, (const u16*)d_in[0], flag);
  hipLaunchKernelGGL(k_normalize, dim3(64, NARR), dim3(256), 0, stream, tab, flag);

  int nchunks = N_ / NC;
  int cn = (NC + 63) / 64;
  for (int b0 = 0; b0 < B_; b0 += G) {
    hipLaunchKernelGGL(k_transpose, dim3(13, 6, G), dim3(256), 0, stream, xn, xT, b0);
    hipLaunchKernelGGL(k_proj, dim3(13, 24, G), dim3(256), 0, stream, xT,
                       Wq, bq, sq, tq, Wk, bk, sk, tk, Wv, bv, sv, tv, qb, kb, vb);
    hipLaunchKernelGGL(k_dwconv, dim3(R_, G), dim3(256), 0, stream, vb, Wvl, bvl, svl, tvl, vlb);
    for (int c = 0; c < nchunks; ++c) {
      int n0 = c * NC;
      hipLaunchKernelGGL(k_scores, dim3(13, cn, H_), dim3(256), 0, stream,
                         qb, kb, ab, Sf, n0, NC, G);
      hipLaunchKernelGGL(k_softmax, dim3(NC, G), dim3(256), 0, stream,
                         Sf, P, th1w, th1b, th2w, th2b, NC);
      hipLaunchKernelGGL(k_pv, dim3(cn, 2, G * H_), dim3(256), 0, stream,
                         P, vb, vlb, obb, n0, NC);
    }
    hipLaunchKernelGGL(k_outproj, dim3(13, 6, G), dim3(256), 0, stream,
                       obb, Wp, bp, sp, tp, out, b0);
  }
}

// Round 5
// 2943.379 us; speedup vs baseline: 1.2508x; 1.2508x over previous
//
#include <hip/hip_runtime.h>
#include <hip/hip_bf16.h>

#define B_ 32
#define DIM_ 384
#define R_ 28
#define N_ 784
#define H_ 8
#define KD_ 32
#define D_ 128
#define DH_ 1024
#define SCALE_ 0.17677669529663687f
#define NARR 26

typedef unsigned short u16;
typedef __attribute__((ext_vector_type(4))) float f32x4;
typedef __attribute__((ext_vector_type(8))) short s16x8;

__device__ __forceinline__ float b2f(u16 b) {
  union { unsigned int u; float f; } v; v.u = ((unsigned int)b) << 16; return v.f;
}
__device__ __forceinline__ u16 f2b(float f) {
  union { float f; unsigned int u; } v; v.f = f;
  unsigned int r = v.u + 0x7fffu + ((v.u >> 16) & 1u);
  return (u16)(r >> 16);
}

// ---------- dtype probe: bf16 data has exp field in a narrow band ----------
__global__ void k_detect(const u16* __restrict__ x, int* __restrict__ flag) {
  __shared__ int cnt;
  if (threadIdx.x == 0) cnt = 0;
  __syncthreads();
  int c = 0;
  for (int i = threadIdx.x; i < 8192; i += 256) {
    int e = (x[i] >> 7) & 0xFF;
    if (e < 64 || e > 160) ++c;
  }
  atomicAdd(&cnt, c);
  __syncthreads();
  if (threadIdx.x == 0) *flag = (cnt > 256) ? 1 : 0;  // 1 => inputs are f32
}

struct NormTab {
  const void* src[NARR];
  u16* dst[NARR];
  int n[NARR];
};

__global__ __launch_bounds__(256) void k_normalize(NormTab tab, const int* __restrict__ flag) {
  int a = blockIdx.y;
  int n = tab.n[a];
  int f = *flag;
  u16* dst = tab.dst[a];
  if (f) {
    const float* s = (const float*)tab.src[a];
    for (int i = blockIdx.x * 256 + threadIdx.x; i < n; i += gridDim.x * 256)
      dst[i] = f2b(s[i]);
  } else {
    const u16* s = (const u16*)tab.src[a];
    for (int i = blockIdx.x * 256 + threadIdx.x; i < n; i += gridDim.x * 256)
      dst[i] = s[i];
  }
}

// 4 waves, block tile 64x64, wave tile 32x32 (2x2 of 16x16x32 bf16 MFMA).
// Both LDS operands stored [out-index][k] with k contiguous (32 bf16/row).
__device__ __forceinline__ void mfma_tile(const u16 (*A)[32], const u16 (*B)[32],
                                          int wm, int wn, int l16, int quad,
                                          f32x4 acc[2][2]) {
  s16x8 a0 = *(const s16x8*)&A[wm * 32 + l16][quad * 8];
  s16x8 a1 = *(const s16x8*)&A[wm * 32 + 16 + l16][quad * 8];
  s16x8 b0 = *(const s16x8*)&B[wn * 32 + l16][quad * 8];
  s16x8 b1 = *(const s16x8*)&B[wn * 32 + 16 + l16][quad * 8];
  acc[0][0] = __builtin_amdgcn_mfma_f32_16x16x32_bf16(a0, b0, acc[0][0], 0, 0, 0);
  acc[0][1] = __builtin_amdgcn_mfma_f32_16x16x32_bf16(a0, b1, acc[0][1], 0, 0, 0);
  acc[1][0] = __builtin_amdgcn_mfma_f32_16x16x32_bf16(a1, b0, acc[1][0], 0, 0, 0);
  acc[1][1] = __builtin_amdgcn_mfma_f32_16x16x32_bf16(a1, b1, acc[1][1], 0, 0, 0);
}

// ---------------- K0: transpose x [b][c][n] -> xT [bl][n][c] ----------------
__global__ __launch_bounds__(256) void k_transpose(const u16* __restrict__ x,
                                                   u16* __restrict__ xT, int b0) {
  __shared__ u16 tile[64][65];
  int nt = blockIdx.x, ct = blockIdx.y, bl = blockIdx.z;
  int t = threadIdx.x;
  int n0 = nt * 64, c0 = ct * 64;
  const u16* xb = x + (size_t)(b0 + bl) * DIM_ * N_;
  int nl = t & 63, cg = t >> 6;
  for (int i = 0; i < 16; ++i) {
    int cl = cg * 16 + i;
    int n = n0 + nl;
    u16 val = 0;
    if (n < N_) val = xb[(size_t)(c0 + cl) * N_ + n];
    tile[cl][nl] = val;
  }
  __syncthreads();
  u16* xTb = xT + (size_t)bl * N_ * DIM_;
  int cl = t & 63, ng = t >> 6;
  for (int i = 0; i < 16; ++i) {
    int n2 = n0 + ng * 16 + i;
    if (n2 < N_) xTb[(size_t)n2 * DIM_ + (c0 + cl)] = tile[cl][ng * 16 + i];
  }
}

// ---------------- K1: fused QKV projection + BN affine ----------------
__global__ __launch_bounds__(256) void k_proj(
    const u16* __restrict__ xT,
    const u16* __restrict__ Wq, const u16* __restrict__ bq, const u16* __restrict__ sq, const u16* __restrict__ tq,
    const u16* __restrict__ Wk, const u16* __restrict__ bk, const u16* __restrict__ sk, const u16* __restrict__ tk,
    const u16* __restrict__ Wv, const u16* __restrict__ bv, const u16* __restrict__ sv, const u16* __restrict__ tv,
    u16* __restrict__ qb, u16* __restrict__ kb, u16* __restrict__ vb) {
  __shared__ __align__(16) u16 Als[64][32];
  __shared__ __align__(16) u16 Bls[64][32];
  int nt = blockIdx.x, mt = blockIdx.y, bl = blockIdx.z;
  int t = threadIdx.x;
  int oc0 = mt * 64;
  const u16 *Wsrc, *bsrc, *ssrc, *tsrc; int obase;
  if (oc0 < 256)      { Wsrc = Wq; bsrc = bq; ssrc = sq; tsrc = tq; obase = oc0; }
  else if (oc0 < 512) { Wsrc = Wk; bsrc = bk; ssrc = sk; tsrc = tk; obase = oc0 - 256; }
  else                { Wsrc = Wv; bsrc = bv; ssrc = sv; tsrc = tv; obase = oc0 - 512; }

  int lane = t & 63, wid = t >> 6;
  int wm = wid & 1, wn = wid >> 1;
  int l16 = lane & 15, quad = lane >> 4;
  int srow = t >> 2, skoff = (t & 3) * 8;

  f32x4 acc[2][2] = {};
  const u16* xTb = xT + (size_t)bl * N_ * DIM_;

  for (int kc = 0; kc < DIM_ / 32; ++kc) {
    int k0 = kc * 32;
    *(s16x8*)&Als[srow][skoff] =
        *(const s16x8*)&Wsrc[(size_t)(obase + srow) * DIM_ + k0 + skoff];
    int n = nt * 64 + srow;
    s16x8 bvv = {};
    if (n < N_) bvv = *(const s16x8*)&xTb[(size_t)n * DIM_ + k0 + skoff];
    *(s16x8*)&Bls[srow][skoff] = bvv;
    __syncthreads();
    mfma_tile(Als, Bls, wm, wn, l16, quad, acc);
    __syncthreads();
  }
  for (int mi = 0; mi < 2; ++mi)
    for (int ni = 0; ni < 2; ++ni)
      for (int r = 0; r < 4; ++r) {
        int row = wm * 32 + mi * 16 + quad * 4 + r;
        int col = nt * 64 + wn * 32 + ni * 16 + l16;
        if (col >= N_) continue;
        int oc = oc0 + row;
        int ol = obase + row;
        float val = acc[mi][ni][r];
        val = (val + b2f(bsrc[ol])) * b2f(ssrc[ol]) + b2f(tsrc[ol]);
        u16 o = f2b(val);
        if (oc < 256) {
          int h = oc >> 5, c = oc & 31;
          qb[(((size_t)bl * H_ + h) * N_ + col) * KD_ + c] = o;
        } else if (oc < 512) {
          int oc2 = oc - 256; int h = oc2 >> 5, c = oc2 & 31;
          kb[(((size_t)bl * H_ + h) * N_ + col) * KD_ + c] = o;
        } else {
          int ch = oc - 512;
          vb[((size_t)bl * DH_ + ch) * N_ + col] = o;
        }
      }
}

// ---------------- K2: depthwise 3x3 conv + affine; wave-per-channel ----------------
// vlb stored [bl][ch][n] (channel-contiguous images, same layout as vb).
__global__ __launch_bounds__(256) void k_dwconv(
    const u16* __restrict__ vb, const u16* __restrict__ Wvl,
    const u16* __restrict__ bvl, const u16* __restrict__ svl, const u16* __restrict__ tvl,
    u16* __restrict__ vlb) {
  __shared__ u16 img[4][N_];
  int cg = blockIdx.x, bl = blockIdx.y;
  int t = threadIdx.x;
  int wid = t >> 6, lane = t & 63;
  int ch = cg * 4 + wid;
  const u16* vp = vb + ((size_t)bl * DH_ + ch) * N_;
  for (int i = lane; i < N_; i += 64) img[wid][i] = vp[i];
  __syncthreads();
  float w[9];
  for (int i = 0; i < 9; ++i) w[i] = b2f(Wvl[ch * 9 + i]);
  float bias = b2f(bvl[ch]), sc = b2f(svl[ch]), sh = b2f(tvl[ch]);
  u16* op = vlb + ((size_t)bl * DH_ + ch) * N_;
  for (int p = lane; p < N_; p += 64) {
    int y = p / R_, x = p - y * R_;
    float acc = 0.f;
    #pragma unroll
    for (int dy = -1; dy <= 1; ++dy) {
      int yy = y + dy;
      if (yy < 0 || yy >= R_) continue;
      #pragma unroll
      for (int dx = -1; dx <= 1; ++dx) {
        int xx = x + dx;
        if (xx < 0 || xx >= R_) continue;
        acc += b2f(img[wid][yy * R_ + xx]) * w[(dy + 1) * 3 + (dx + 1)];
      }
    }
    op[p] = f2b((acc + bias) * sc + sh);
  }
}

// ---------------- K3: raw scores (f32) Sf[bl][h][nloc][m] = scale*q.k + ab ----------------
__global__ __launch_bounds__(256) void k_scores(
    const u16* __restrict__ qb, const u16* __restrict__ kb, const u16* __restrict__ ab,
    float* __restrict__ Sf, int n0, int NC, int G) {
  __shared__ float abrow[N_];
  __shared__ float biasT[64][64];
  __shared__ __align__(16) u16 Als[64][32];
  __shared__ __align__(16) u16 Bls[64][32];
  int mt = blockIdx.x, ntl = blockIdx.y, h = blockIdx.z;
  int t = threadIdx.x;
  for (int i = t; i < N_; i += 256) abrow[i] = b2f(ab[h * N_ + i]);
  __syncthreads();
  int jm = t & 63, ig = t >> 6;
  for (int ii = 0; ii < 16; ++ii) {
    int i = ig * 16 + ii;
    int n_g = n0 + ntl * 64 + i;
    int m_g = mt * 64 + jm;
    float bv = 0.f;
    if (n_g < N_ && m_g < N_) {
      int yn = n_g / R_, xn = n_g - yn * R_;
      int ym = m_g / R_, xm = m_g - ym * R_;
      int dy = yn - ym; if (dy < 0) dy = -dy;
      int dx = xn - xm; if (dx < 0) dx = -dx;
      bv = abrow[dy * R_ + dx];
    }
    biasT[i][jm] = bv;
  }
  int lane = t & 63, wid = t >> 6;
  int wm = wid & 1, wn = wid >> 1;
  int l16 = lane & 15, quad = lane >> 4;
  int srow = t >> 2, skoff = (t & 3) * 8;

  for (int bl = 0; bl < G; ++bl) {
    __syncthreads();
    {
      int nloc = ntl * 64 + srow;
      int n_g = n0 + nloc;
      s16x8 av = {};
      if (nloc < NC && n_g < N_)
        av = *(const s16x8*)&qb[(((size_t)bl * H_ + h) * N_ + n_g) * KD_ + skoff];
      *(s16x8*)&Als[srow][skoff] = av;
      int m_g = mt * 64 + srow;
      s16x8 bv2 = {};
      if (m_g < N_)
        bv2 = *(const s16x8*)&kb[(((size_t)bl * H_ + h) * N_ + m_g) * KD_ + skoff];
      *(s16x8*)&Bls[srow][skoff] = bv2;
    }
    __syncthreads();
    f32x4 acc[2][2] = {};
    mfma_tile(Als, Bls, wm, wn, l16, quad, acc);
    for (int mi = 0; mi < 2; ++mi)
      for (int ni = 0; ni < 2; ++ni)
        for (int r = 0; r < 4; ++r) {
          int row = wm * 32 + mi * 16 + quad * 4 + r;
          int col = wn * 32 + ni * 16 + l16;
          int nloc = ntl * 64 + row;
          int m_g = mt * 64 + col;
          if (nloc < NC && (n0 + nloc) < N_ && m_g < N_) {
            Sf[(((size_t)bl * H_ + h) * NC + nloc) * N_ + m_g] =
                acc[mi][ni][r] * SCALE_ + biasT[row][col];
          }
        }
  }
}

// ---------------- K4: th1-mix + softmax + th2-mix; f32 in, bf16 probs out ----------------
__global__ __launch_bounds__(256) void k_softmax(
    const float* __restrict__ Sf, u16* __restrict__ P,
    const u16* __restrict__ th1w, const u16* __restrict__ th1b,
    const u16* __restrict__ th2w, const u16* __restrict__ th2b, int NC) {
  __shared__ float sm[H_][N_];
  __shared__ float w1[64], bb1[8], w2[64], bb2[8], linv[8];
  int ncl = blockIdx.x, bl = blockIdx.y;
  int t = threadIdx.x;
  if (t < 64) { w1[t] = b2f(th1w[t]); w2[t] = b2f(th2w[t]); }
  if (t < 8)  { bb1[t] = b2f(th1b[t]); bb2[t] = b2f(th2b[t]); }
  __syncthreads();
  size_t base = ((size_t)bl * H_ * NC + ncl) * N_;
  size_t hstr = (size_t)NC * N_;
  for (int m = t; m < N_; m += 256) {
    float s[8];
    for (int h = 0; h < 8; ++h) s[h] = Sf[base + h * hstr + m];
    for (int g = 0; g < 8; ++g) {
      float a = bb1[g];
      for (int h = 0; h < 8; ++h) a += w1[g * 8 + h] * s[h];
      sm[g][m] = a;
    }
  }
  __syncthreads();
  int lane = t & 63, wid = t >> 6;
  for (int gi = 0; gi < 2; ++gi) {
    int g = wid + gi * 4;
    float mx = -1e30f;
    for (int m = lane; m < N_; m += 64) mx = fmaxf(mx, sm[g][m]);
    for (int off = 32; off >= 1; off >>= 1) mx = fmaxf(mx, __shfl_xor(mx, off));
    float sum = 0.f;
    for (int m = lane; m < N_; m += 64) {
      float e = __expf(sm[g][m] - mx);
      sm[g][m] = e;
      sum += e;
    }
    for (int off = 32; off >= 1; off >>= 1) sum += __shfl_xor(sum, off);
    if (lane == 0) linv[g] = 1.f / sum;
  }
  __syncthreads();
  float li[8];
  for (int g = 0; g < 8; ++g) li[g] = linv[g];
  for (int m = t; m < N_; m += 256) {
    float p[8];
    for (int g = 0; g < 8; ++g) p[g] = sm[g][m] * li[g];
    for (int f = 0; f < 8; ++f) {
      float a = bb2[f];
      for (int g = 0; g < 8; ++g) a += w2[f * 8 + g] * p[g];
      P[base + f * hstr + m] = f2b(a);
    }
  }
}

// ---------------- K5: O'[bl][n][ch] = relu(attn @ V + vl) ----------------
__global__ __launch_bounds__(256) void k_pv(
    const u16* __restrict__ P, const u16* __restrict__ vb, const u16* __restrict__ vlb,
    u16* __restrict__ ob, int n0, int NC) {
  __shared__ __align__(16) u16 Als[64][32];  // V rows (d)
  __shared__ __align__(16) u16 Bls[64][32];  // attn rows (n)
  int ntl = blockIdx.x, dt = blockIdx.y, z = blockIdx.z;
  int bl = z >> 3, f = z & 7;
  int t = threadIdx.x;
  int lane = t & 63, wid = t >> 6;
  int wm = wid & 1, wn = wid >> 1;
  int l16 = lane & 15, quad = lane >> 4;
  int srow = t >> 2, skoff = (t & 3) * 8;

  f32x4 acc[2][2] = {};
  const u16* vsrc = vb + ((size_t)bl * DH_ + f * D_ + dt * 64) * N_;
  const u16* asrc = P + ((size_t)bl * H_ + f) * NC * N_;

  for (int kc = 0; kc < 25; ++kc) {
    int kk = kc * 32 + skoff;
    s16x8 av = {}, bv = {};
    if (kk + 8 <= N_) av = *(const s16x8*)&vsrc[(size_t)srow * N_ + kk];
    int nloc = ntl * 64 + srow;
    if (nloc < NC && kk + 8 <= N_) bv = *(const s16x8*)&asrc[(size_t)nloc * N_ + kk];
    *(s16x8*)&Als[srow][skoff] = av;
    *(s16x8*)&Bls[srow][skoff] = bv;
    __syncthreads();
    mfma_tile(Als, Bls, wm, wn, l16, quad, acc);
    __syncthreads();
  }
  for (int mi = 0; mi < 2; ++mi)
    for (int ni = 0; ni < 2; ++ni) {
      int row = wm * 32 + mi * 16 + quad * 4;  // d local, 4 regs = 4 contiguous d
      int col = wn * 32 + ni * 16 + l16;       // token local
      int nloc = ntl * 64 + col;
      if (nloc >= NC || (n0 + nloc) >= N_) continue;
      int ch = f * D_ + dt * 64 + row;
      // vlb is [bl][ch][n]: 4 loads, lane-coalesced over tokens
      size_t vaddr = ((size_t)bl * DH_ + ch) * N_ + (n0 + nloc);
      float o0 = acc[mi][ni][0] + b2f(vlb[vaddr]);
      float o1 = acc[mi][ni][1] + b2f(vlb[vaddr + N_]);
      float o2 = acc[mi][ni][2] + b2f(vlb[vaddr + 2 * N_]);
      float o3 = acc[mi][ni][3] + b2f(vlb[vaddr + 3 * N_]);
      size_t addr = ((size_t)bl * N_ + (n0 + nloc)) * DH_ + ch;
      ushort4 o4;
      o4.x = f2b(o0 > 0.f ? o0 : 0.f);
      o4.y = f2b(o1 > 0.f ? o1 : 0.f);
      o4.z = f2b(o2 > 0.f ? o2 : 0.f);
      o4.w = f2b(o3 > 0.f ? o3 : 0.f);
      *(ushort4*)&ob[addr] = o4;
    }
}

// ---------------- K6: out[b0+bl][oc][n] = affine(Wp @ O' + bp), f32 output ----------------
__global__ __launch_bounds__(256) void k_outproj(
    const u16* __restrict__ ob, const u16* __restrict__ Wp,
    const u16* __restrict__ bp, const u16* __restrict__ sp, const u16* __restrict__ tp,
    float* __restrict__ out, int b0) {
  __shared__ __align__(16) u16 Als[64][32];
  __shared__ __align__(16) u16 Bls[64][32];
  int nt = blockIdx.x, mt = blockIdx.y, bl = blockIdx.z;
  int t = threadIdx.x;
  int lane = t & 63, wid = t >> 6;
  int wm = wid & 1, wn = wid >> 1;
  int l16 = lane & 15, quad = lane >> 4;
  int srow = t >> 2, skoff = (t & 3) * 8;

  f32x4 acc[2][2] = {};
  const u16* obb = ob + (size_t)bl * N_ * DH_;

  for (int kc = 0; kc < DH_ / 32; ++kc) {
    int k0 = kc * 32;
    *(s16x8*)&Als[srow][skoff] =
        *(const s16x8*)&Wp[(size_t)(mt * 64 + srow) * DH_ + k0 + skoff];
    int n = nt * 64 + srow;
    s16x8 bvv = {};
    if (n < N_) bvv = *(const s16x8*)&obb[(size_t)n * DH_ + k0 + skoff];
    *(s16x8*)&Bls[srow][skoff] = bvv;
    __syncthreads();
    mfma_tile(Als, Bls, wm, wn, l16, quad, acc);
    __syncthreads();
  }
  for (int mi = 0; mi < 2; ++mi)
    for (int ni = 0; ni < 2; ++ni)
      for (int r = 0; r < 4; ++r) {
        int oc = mt * 64 + wm * 32 + mi * 16 + quad * 4 + r;
        int n = nt * 64 + wn * 32 + ni * 16 + l16;
        if (n >= N_) continue;
        float val = (acc[mi][ni][r] + b2f(bp[oc])) * b2f(sp[oc]) + b2f(tp[oc]);
        out[((size_t)(b0 + bl) * DIM_ + oc) * N_ + n] = val;  // f32 output
      }
}

extern "C" void kernel_launch(void* const* d_in, const int* in_sizes, int n_in,
                              void* d_out, int out_size, void* d_ws, size_t ws_size,
                              hipStream_t stream) {
  (void)n_in; (void)out_size;
  float* out = (float*)d_out;  // reference output dtype is float32

  char* ws = (char*)d_ws;
  size_t off = 0;
  auto alloc = [&](size_t bytes) -> void* {
    void* p = ws + off;
    off += (bytes + 255) & ~(size_t)255;
    return p;
  };

  // --- fixed region: dtype flag + normalized bf16 copies of the 26 tensor inputs ---
  int* flag = (int*)alloc(256);
  NormTab tab;
  u16* nrm[NARR];
  for (int i = 0; i < NARR; ++i) {
    int n = in_sizes[i];
    nrm[i] = (u16*)alloc((size_t)n * 2);
    tab.src[i] = d_in[i];
    tab.dst[i] = nrm[i];
    tab.n[i] = n;
  }
  size_t fixed = off;

  const u16* xn   = nrm[0];
  const u16* Wq   = nrm[1];
  const u16* bq   = nrm[2];
  const u16* sq   = nrm[3];
  const u16* tq   = nrm[4];
  const u16* Wk   = nrm[5];
  const u16* bk   = nrm[6];
  const u16* sk   = nrm[7];
  const u16* tk   = nrm[8];
  const u16* Wv   = nrm[9];
  const u16* bv   = nrm[10];
  const u16* sv   = nrm[11];
  const u16* tv   = nrm[12];
  const u16* Wvl  = nrm[13];
  const u16* bvl  = nrm[14];
  const u16* svl  = nrm[15];
  const u16* tvl  = nrm[16];
  const u16* th1w = nrm[17];
  const u16* th1b = nrm[18];
  const u16* th2w = nrm[19];
  const u16* th2b = nrm[20];
  const u16* ab   = nrm[21];
  const u16* Wp   = nrm[22];
  const u16* bp   = nrm[23];
  const u16* sp   = nrm[24];
  const u16* tp   = nrm[25];

  // --- pick batch-group size G and n-chunk NC so everything fits ws_size ---
  auto footprint = [fixed](int G, int NC) -> size_t {
    auto al = [](size_t b) { return (b + 255) & ~(size_t)255; };
    size_t a = fixed;
    a += al((size_t)G * H_ * N_ * KD_ * 2);   // qb
    a += al((size_t)G * H_ * N_ * KD_ * 2);   // kb
    a += al((size_t)G * DH_ * N_ * 2);        // vb
    a += al((size_t)G * DH_ * N_ * 2);        // vlb
    a += al((size_t)G * N_ * DH_ * 2);        // obb
    size_t xtb = (size_t)G * N_ * DIM_ * 2;
    size_t sb = (size_t)G * H_ * NC * N_ * 4; // Sf (f32), aliases xT
    a += al(sb > xtb ? sb : xtb);
    a += al((size_t)G * H_ * NC * N_ * 2);    // P (bf16 probs)
    return a;
  };
  const int Gs[6] = {32, 16, 8, 4, 2, 1};
  const int NCs[6] = {784, 392, 196, 112, 56, 28};
  int G = 1, NC = 28;
  bool found = false;
  for (int gi = 0; gi < 6 && !found; ++gi)
    for (int ci = 0; ci < 6 && !found; ++ci)
      if (footprint(Gs[gi], NCs[ci]) <= ws_size) { G = Gs[gi]; NC = NCs[ci]; found = true; }

  u16* qb  = (u16*)alloc((size_t)G * H_ * N_ * KD_ * 2);
  u16* kb  = (u16*)alloc((size_t)G * H_ * N_ * KD_ * 2);
  u16* vb  = (u16*)alloc((size_t)G * DH_ * N_ * 2);
  u16* vlb = (u16*)alloc((size_t)G * DH_ * N_ * 2);   // [bl][ch][n]
  u16* obb = (u16*)alloc((size_t)G * N_ * DH_ * 2);
  size_t xtb = (size_t)G * N_ * DIM_ * 2;
  size_t sb = (size_t)G * H_ * NC * N_ * 4;
  float* Sf = (float*)alloc(sb > xtb ? sb : xtb);
  u16* xT = (u16*)Sf;  // xT dead before Sf is first written
  u16* P  = (u16*)alloc((size_t)G * H_ * NC * N_ * 2);

  // --- dtype probe + input normalization (runs once per launch) ---
  hipLaunchKernelGGL(k_detect, dim3(1), dim3(256), 0, stream, (const u16*)d_in[0], flag);
  hipLaunchKernelGGL(k_normalize, dim3(64, NARR), dim3(256), 0, stream, tab, flag);

  int nchunks = N_ / NC;
  int cn = (NC + 63) / 64;
  for (int b0 = 0; b0 < B_; b0 += G) {
    hipLaunchKernelGGL(k_transpose, dim3(13, 6, G), dim3(256), 0, stream, xn, xT, b0);
    hipLaunchKernelGGL(k_proj, dim3(13, 24, G), dim3(256), 0, stream, xT,
                       Wq, bq, sq, tq, Wk, bk, sk, tk, Wv, bv, sv, tv, qb, kb, vb);
    hipLaunchKernelGGL(k_dwconv, dim3(DH_ / 4, G), dim3(256), 0, stream,
                       vb, Wvl, bvl, svl, tvl, vlb);
    for (int c = 0; c < nchunks; ++c) {
      int n0 = c * NC;
      hipLaunchKernelGGL(k_scores, dim3(13, cn, H_), dim3(256), 0, stream,
                         qb, kb, ab, Sf, n0, NC, G);
      hipLaunchKernelGGL(k_softmax, dim3(NC, G), dim3(256), 0, stream,
                         Sf, P, th1w, th1b, th2w, th2b, NC);
      hipLaunchKernelGGL(k_pv, dim3(cn, 2, G * H_), dim3(256), 0, stream,
                         P, vb, vlb, obb, n0, NC);
    }
    hipLaunchKernelGGL(k_outproj, dim3(13, 6, G), dim3(256), 0, stream,
                       obb, Wp, bp, sp, tp, out, b0);
  }
}

// Round 6
// 1709.878 us; speedup vs baseline: 2.1531x; 1.7214x over previous
//
#include <hip/hip_runtime.h>
#include <hip/hip_bf16.h>

#define B_ 32
#define DIM_ 384
#define R_ 28
#define N_ 784
#define H_ 8
#define KD_ 32
#define D_ 128
#define DH_ 1024
#define SCALE_ 0.17677669529663687f

typedef unsigned short u16;
typedef __attribute__((ext_vector_type(4))) float f32x4;
typedef __attribute__((ext_vector_type(8))) short s16x8;

__device__ __forceinline__ float b2f(u16 b) {
  union { unsigned int u; float f; } v; v.u = ((unsigned int)b) << 16; return v.f;
}
__device__ __forceinline__ u16 f2b(float f) {
  union { float f; unsigned int u; } v; v.f = f;
  unsigned int r = v.u + 0x7fffu + ((v.u >> 16) & 1u);
  return (u16)(r >> 16);
}

// ---------------- weight convert f32 -> bf16 (4 arrays) ----------------
struct CvtTab { const float* src[4]; u16* dst[4]; int n[4]; };

__global__ __launch_bounds__(256) void k_cvt(CvtTab tab) {
  int a = blockIdx.y;
  int n4 = tab.n[a] >> 2;
  const float4* s = (const float4*)tab.src[a];
  ushort4* d = (ushort4*)tab.dst[a];
  for (int i = blockIdx.x * 256 + threadIdx.x; i < n4; i += gridDim.x * 256) {
    float4 v = s[i];
    ushort4 o;
    o.x = f2b(v.x); o.y = f2b(v.y); o.z = f2b(v.z); o.w = f2b(v.w);
    d[i] = o;
  }
}

// ---------------- K0: transpose x(f32) [b][c][n] -> xT(bf16) [bl][n][c] ----------------
__global__ __launch_bounds__(256) void k_transpose(const float* __restrict__ x,
                                                   u16* __restrict__ xT, int b0) {
  __shared__ u16 tile[64][65];
  int nt = blockIdx.x, ct = blockIdx.y, bl = blockIdx.z;
  int t = threadIdx.x;
  int n0 = nt * 64, c0 = ct * 64;
  const float* xb = x + (size_t)(b0 + bl) * DIM_ * N_;
  int nl = t & 63, cg = t >> 6;
  for (int i = 0; i < 16; ++i) {
    int cl = cg * 16 + i;
    int n = n0 + nl;
    u16 val = 0;
    if (n < N_) val = f2b(xb[(size_t)(c0 + cl) * N_ + n]);
    tile[cl][nl] = val;
  }
  __syncthreads();
  u16* xTb = xT + (size_t)bl * N_ * DIM_;
  int cl = t & 63, ng = t >> 6;
  for (int i = 0; i < 16; ++i) {
    int n2 = n0 + ng * 16 + i;
    if (n2 < N_) xTb[(size_t)n2 * DIM_ + (c0 + cl)] = tile[cl][ng * 16 + i];
  }
}

// ---------------- K1: fused QKV projection + BN affine (no LDS) ----------------
// A = weights (rows oc, K=c), B = xT (rows n, K=c). acc row=oc, col=n.
__global__ __launch_bounds__(256) void k_proj(
    const u16* __restrict__ xT,
    const u16* __restrict__ wqb, const u16* __restrict__ wkb, const u16* __restrict__ wvb,
    const float* __restrict__ bq, const float* __restrict__ sq, const float* __restrict__ tq,
    const float* __restrict__ bk, const float* __restrict__ sk, const float* __restrict__ tk,
    const float* __restrict__ bv, const float* __restrict__ sv, const float* __restrict__ tv,
    u16* __restrict__ qb, u16* __restrict__ kb, u16* __restrict__ vb) {
  int nt = blockIdx.x, mt = blockIdx.y, bl = blockIdx.z;
  int t = threadIdx.x;
  int oc0 = mt * 64;
  const u16* Wsrc; const float *bsrc, *ssrc, *tsrc; int obase;
  if (oc0 < 256)      { Wsrc = wqb; bsrc = bq; ssrc = sq; tsrc = tq; obase = oc0; }
  else if (oc0 < 512) { Wsrc = wkb; bsrc = bk; ssrc = sk; tsrc = tk; obase = oc0 - 256; }
  else                { Wsrc = wvb; bsrc = bv; ssrc = sv; tsrc = tv; obase = oc0 - 512; }

  int lane = t & 63, wid = t >> 6;
  int wm = wid & 1, wn = wid >> 1;
  int l16 = lane & 15, quad = lane >> 4;

  const u16* xTb = xT + (size_t)bl * N_ * DIM_;
  int ra0 = obase + wm * 32 + l16;           // weight rows (always valid in-tile)
  int ra1 = ra0 + 16;
  int n0g = nt * 64 + wn * 32 + l16;
  int rb0 = n0g < N_ ? n0g : N_ - 1;         // clamp; garbage discarded on store
  int rb1 = (n0g + 16) < N_ ? n0g + 16 : N_ - 1;

  f32x4 acc[2][2] = {};
  for (int kc = 0; kc < DIM_ / 32; ++kc) {
    int k0 = kc * 32 + quad * 8;
    s16x8 a0 = *(const s16x8*)&Wsrc[(size_t)ra0 * DIM_ + k0];
    s16x8 a1 = *(const s16x8*)&Wsrc[(size_t)ra1 * DIM_ + k0];
    s16x8 b0 = *(const s16x8*)&xTb[(size_t)rb0 * DIM_ + k0];
    s16x8 b1 = *(const s16x8*)&xTb[(size_t)rb1 * DIM_ + k0];
    acc[0][0] = __builtin_amdgcn_mfma_f32_16x16x32_bf16(a0, b0, acc[0][0], 0, 0, 0);
    acc[0][1] = __builtin_amdgcn_mfma_f32_16x16x32_bf16(a0, b1, acc[0][1], 0, 0, 0);
    acc[1][0] = __builtin_amdgcn_mfma_f32_16x16x32_bf16(a1, b0, acc[1][0], 0, 0, 0);
    acc[1][1] = __builtin_amdgcn_mfma_f32_16x16x32_bf16(a1, b1, acc[1][1], 0, 0, 0);
  }
  for (int mi = 0; mi < 2; ++mi)
    for (int ni = 0; ni < 2; ++ni) {
      int row0 = wm * 32 + mi * 16 + quad * 4;
      int col = nt * 64 + wn * 32 + ni * 16 + l16;
      if (col >= N_) continue;
      int ol0 = obase + row0;
      float4 bb = *(const float4*)&bsrc[ol0];
      float4 ss = *(const float4*)&ssrc[ol0];
      float4 tt = *(const float4*)&tsrc[ol0];
      float v0 = (acc[mi][ni][0] + bb.x) * ss.x + tt.x;
      float v1 = (acc[mi][ni][1] + bb.y) * ss.y + tt.y;
      float v2 = (acc[mi][ni][2] + bb.z) * ss.z + tt.z;
      float v3 = (acc[mi][ni][3] + bb.w) * ss.w + tt.w;
      int oc = oc0 + row0;
      if (oc < 512) {
        // q/k: [bl][h][n][c]; c = oc&31 contiguous over the 4 regs
        int h = (oc & 255) >> 5, c0 = oc & 31;
        u16* dst = (oc < 256) ? qb : kb;
        ushort4 o;
        o.x = f2b(v0); o.y = f2b(v1); o.z = f2b(v2); o.w = f2b(v3);
        *(ushort4*)&dst[(((size_t)bl * H_ + h) * N_ + col) * KD_ + c0] = o;
      } else {
        int ch = oc - 512;
        vb[((size_t)bl * DH_ + ch) * N_ + col] = f2b(v0);
        vb[((size_t)bl * DH_ + ch + 1) * N_ + col] = f2b(v1);
        vb[((size_t)bl * DH_ + ch + 2) * N_ + col] = f2b(v2);
        vb[((size_t)bl * DH_ + ch + 3) * N_ + col] = f2b(v3);
      }
    }
}

// ---------------- K2: depthwise 3x3 conv + affine; wave-per-channel ----------------
__global__ __launch_bounds__(256) void k_dwconv(
    const u16* __restrict__ vb, const float* __restrict__ Wvl,
    const float* __restrict__ bvl, const float* __restrict__ svl, const float* __restrict__ tvl,
    u16* __restrict__ vlb) {
  __shared__ u16 img[4][N_];
  int cg = blockIdx.x, bl = blockIdx.y;
  int t = threadIdx.x;
  int wid = t >> 6, lane = t & 63;
  int ch = cg * 4 + wid;
  const u16* vp = vb + ((size_t)bl * DH_ + ch) * N_;
  for (int i = lane; i < N_; i += 64) img[wid][i] = vp[i];
  __syncthreads();
  float w[9];
  for (int i = 0; i < 9; ++i) w[i] = Wvl[ch * 9 + i];
  float bias = bvl[ch], sc = svl[ch], sh = tvl[ch];
  u16* op = vlb + ((size_t)bl * DH_ + ch) * N_;
  for (int p = lane; p < N_; p += 64) {
    int y = p / R_, x = p - y * R_;
    float acc = 0.f;
    #pragma unroll
    for (int dy = -1; dy <= 1; ++dy) {
      int yy = y + dy;
      if (yy < 0 || yy >= R_) continue;
      #pragma unroll
      for (int dx = -1; dx <= 1; ++dx) {
        int xx = x + dx;
        if (xx < 0 || xx >= R_) continue;
        acc += b2f(img[wid][yy * R_ + xx]) * w[(dy + 1) * 3 + (dx + 1)];
      }
    }
    op[p] = f2b((acc + bias) * sc + sh);
  }
}

// ---------------- K3: raw scores (f32), no LDS staging for q/k ----------------
// A = keys (rows m), B = queries (rows n). acc row=m, col=n -> f32x4 stores along m.
__global__ __launch_bounds__(256) void k_scores(
    const u16* __restrict__ qb, const u16* __restrict__ kb, const float* __restrict__ ab,
    float* __restrict__ Sf, int n0, int NC, int G) {
  __shared__ float biasT[64][68];  // [n_local][m_local], pad 68: 2-way LDS aliasing only
  int mt = blockIdx.x, ntl = blockIdx.y, h = blockIdx.z;
  int t = threadIdx.x;
  const float* abh = ab + (size_t)h * N_;
  for (int idx = t; idx < 4096; idx += 256) {
    int nl = idx >> 6, ml = idx & 63;
    int n_g = n0 + ntl * 64 + nl;
    int m_g = mt * 64 + ml;
    float bv = 0.f;
    if (n_g < N_ && m_g < N_) {
      int yn = n_g / R_, xn = n_g - yn * R_;
      int ym = m_g / R_, xm = m_g - ym * R_;
      int dy = yn - ym; if (dy < 0) dy = -dy;
      int dx = xn - xm; if (dx < 0) dx = -dx;
      bv = abh[dy * R_ + dx];
    }
    biasT[nl][ml] = bv;
  }
  __syncthreads();

  int lane = t & 63, wid = t >> 6;
  int wm = wid & 1, wn = wid >> 1;
  int l16 = lane & 15, quad = lane >> 4;
  int koff = quad * 8;

  int ma0 = mt * 64 + wm * 32 + l16;
  int ma1 = ma0 + 16;
  int ra0 = ma0 < N_ ? ma0 : N_ - 1;
  int ra1 = ma1 < N_ ? ma1 : N_ - 1;
  int ng0 = n0 + ntl * 64 + wn * 32 + l16;
  int rb0 = ng0 < N_ ? ng0 : N_ - 1;
  int rb1 = (ng0 + 16) < N_ ? ng0 + 16 : N_ - 1;

  for (int bl = 0; bl < G; ++bl) {
    size_t hb = ((size_t)bl * H_ + h) * N_;
    s16x8 a0 = *(const s16x8*)&kb[(hb + ra0) * KD_ + koff];
    s16x8 a1 = *(const s16x8*)&kb[(hb + ra1) * KD_ + koff];
    s16x8 b0 = *(const s16x8*)&qb[(hb + rb0) * KD_ + koff];
    s16x8 b1 = *(const s16x8*)&qb[(hb + rb1) * KD_ + koff];
    f32x4 acc[2][2] = {};
    acc[0][0] = __builtin_amdgcn_mfma_f32_16x16x32_bf16(a0, b0, acc[0][0], 0, 0, 0);
    acc[0][1] = __builtin_amdgcn_mfma_f32_16x16x32_bf16(a0, b1, acc[0][1], 0, 0, 0);
    acc[1][0] = __builtin_amdgcn_mfma_f32_16x16x32_bf16(a1, b0, acc[1][0], 0, 0, 0);
    acc[1][1] = __builtin_amdgcn_mfma_f32_16x16x32_bf16(a1, b1, acc[1][1], 0, 0, 0);
    for (int mi = 0; mi < 2; ++mi)
      for (int ni = 0; ni < 2; ++ni) {
        int ml0 = wm * 32 + mi * 16 + quad * 4;   // local m, 4 contiguous
        int nl = wn * 32 + ni * 16 + l16;         // local n
        int nloc = ntl * 64 + nl;
        if (nloc >= NC || (n0 + nloc) >= N_) continue;
        int m_g0 = mt * 64 + ml0;
        f32x4 bias4 = *(const f32x4*)&biasT[nl][ml0];
        f32x4 sv;
        sv[0] = acc[mi][ni][0] * SCALE_ + bias4[0];
        sv[1] = acc[mi][ni][1] * SCALE_ + bias4[1];
        sv[2] = acc[mi][ni][2] * SCALE_ + bias4[2];
        sv[3] = acc[mi][ni][3] * SCALE_ + bias4[3];
        float* dst = &Sf[(((size_t)bl * H_ + h) * NC + nloc) * N_ + m_g0];
        if (m_g0 + 3 < N_) {
          *(f32x4*)dst = sv;
        } else {
          for (int r = 0; r < 4; ++r) if (m_g0 + r < N_) dst[r] = sv[r];
        }
      }
  }
}

// ---------------- K4: th1-mix + softmax + th2-mix; f32 in, bf16 probs out ----------------
__global__ __launch_bounds__(256) void k_softmax(
    const float* __restrict__ Sf, u16* __restrict__ P,
    const float* __restrict__ th1w, const float* __restrict__ th1b,
    const float* __restrict__ th2w, const float* __restrict__ th2b, int NC) {
  __shared__ float sm[H_][N_];
  __shared__ float w1[64], bb1[8], w2[64], bb2[8], linv[8];
  int ncl = blockIdx.x, bl = blockIdx.y;
  int t = threadIdx.x;
  if (t < 64) { w1[t] = th1w[t]; w2[t] = th2w[t]; }
  if (t < 8)  { bb1[t] = th1b[t]; bb2[t] = th2b[t]; }
  __syncthreads();
  size_t base = ((size_t)bl * H_ * NC + ncl) * N_;
  size_t hstr = (size_t)NC * N_;
  for (int m = t; m < N_; m += 256) {
    float s[8];
    for (int h = 0; h < 8; ++h) s[h] = Sf[base + h * hstr + m];
    for (int g = 0; g < 8; ++g) {
      float a = bb1[g];
      for (int h = 0; h < 8; ++h) a += w1[g * 8 + h] * s[h];
      sm[g][m] = a;
    }
  }
  __syncthreads();
  int lane = t & 63, wid = t >> 6;
  for (int gi = 0; gi < 2; ++gi) {
    int g = wid + gi * 4;
    float mx = -1e30f;
    for (int m = lane; m < N_; m += 64) mx = fmaxf(mx, sm[g][m]);
    for (int off = 32; off >= 1; off >>= 1) mx = fmaxf(mx, __shfl_xor(mx, off));
    float sum = 0.f;
    for (int m = lane; m < N_; m += 64) {
      float e = __expf(sm[g][m] - mx);
      sm[g][m] = e;
      sum += e;
    }
    for (int off = 32; off >= 1; off >>= 1) sum += __shfl_xor(sum, off);
    if (lane == 0) linv[g] = 1.f / sum;
  }
  __syncthreads();
  float li[8];
  for (int g = 0; g < 8; ++g) li[g] = linv[g];
  for (int m = t; m < N_; m += 256) {
    float p[8];
    for (int g = 0; g < 8; ++g) p[g] = sm[g][m] * li[g];
    for (int f = 0; f < 8; ++f) {
      float a = bb2[f];
      for (int g = 0; g < 8; ++g) a += w2[f * 8 + g] * p[g];
      P[base + f * hstr + m] = f2b(a);
    }
  }
}

// ---------------- K5: O'[bl][n][ch] = relu(attn @ V + vl), no LDS ----------------
// A = V (rows d, K=m), B = P (rows n, K=m). acc row=d, col=n.
__global__ __launch_bounds__(256) void k_pv(
    const u16* __restrict__ P, const u16* __restrict__ vb, const u16* __restrict__ vlb,
    u16* __restrict__ ob, int n0, int NC) {
  int ntl = blockIdx.x, dt = blockIdx.y, z = blockIdx.z;
  int bl = z >> 3, f = z & 7;
  int t = threadIdx.x;
  int lane = t & 63, wid = t >> 6;
  int wm = wid & 1, wn = wid >> 1;
  int l16 = lane & 15, quad = lane >> 4;

  const u16* vsrc = vb + ((size_t)bl * DH_ + f * D_ + dt * 64) * N_;
  const u16* asrc = P + ((size_t)bl * H_ + f) * (size_t)NC * N_;

  int da0 = wm * 32 + l16, da1 = da0 + 16;            // V rows (d-local), always valid
  int nl0 = ntl * 64 + wn * 32 + l16;
  int rb0 = nl0 < NC ? nl0 : NC - 1;
  int rb1 = (nl0 + 16) < NC ? nl0 + 16 : NC - 1;

  f32x4 acc[2][2] = {};
  for (int kc = 0; kc < 25; ++kc) {
    int kk = kc * 32 + quad * 8;
    s16x8 a0 = {}, a1 = {}, b0 = {}, b1 = {};
    if (kk + 8 <= N_) {
      a0 = *(const s16x8*)&vsrc[(size_t)da0 * N_ + kk];
      a1 = *(const s16x8*)&vsrc[(size_t)da1 * N_ + kk];
      b0 = *(const s16x8*)&asrc[(size_t)rb0 * N_ + kk];
      b1 = *(const s16x8*)&asrc[(size_t)rb1 * N_ + kk];
    }
    acc[0][0] = __builtin_amdgcn_mfma_f32_16x16x32_bf16(a0, b0, acc[0][0], 0, 0, 0);
    acc[0][1] = __builtin_amdgcn_mfma_f32_16x16x32_bf16(a0, b1, acc[0][1], 0, 0, 0);
    acc[1][0] = __builtin_amdgcn_mfma_f32_16x16x32_bf16(a1, b0, acc[1][0], 0, 0, 0);
    acc[1][1] = __builtin_amdgcn_mfma_f32_16x16x32_bf16(a1, b1, acc[1][1], 0, 0, 0);
  }
  for (int mi = 0; mi < 2; ++mi)
    for (int ni = 0; ni < 2; ++ni) {
      int row = wm * 32 + mi * 16 + quad * 4;
      int col = wn * 32 + ni * 16 + l16;
      int nloc = ntl * 64 + col;
      if (nloc >= NC || (n0 + nloc) >= N_) continue;
      int ch = f * D_ + dt * 64 + row;
      size_t vaddr = ((size_t)bl * DH_ + ch) * N_ + (n0 + nloc);
      float o0 = acc[mi][ni][0] + b2f(vlb[vaddr]);
      float o1 = acc[mi][ni][1] + b2f(vlb[vaddr + N_]);
      float o2 = acc[mi][ni][2] + b2f(vlb[vaddr + 2 * N_]);
      float o3 = acc[mi][ni][3] + b2f(vlb[vaddr + 3 * N_]);
      size_t addr = ((size_t)bl * N_ + (n0 + nloc)) * DH_ + ch;
      ushort4 o4;
      o4.x = f2b(o0 > 0.f ? o0 : 0.f);
      o4.y = f2b(o1 > 0.f ? o1 : 0.f);
      o4.z = f2b(o2 > 0.f ? o2 : 0.f);
      o4.w = f2b(o3 > 0.f ? o3 : 0.f);
      *(ushort4*)&ob[addr] = o4;
    }
}

// ---------------- K6: out = affine(Wp @ O' + bp), f32 output, no LDS ----------------
__global__ __launch_bounds__(256) void k_outproj(
    const u16* __restrict__ ob, const u16* __restrict__ wpb,
    const float* __restrict__ bp, const float* __restrict__ sp, const float* __restrict__ tp,
    float* __restrict__ out, int b0) {
  int nt = blockIdx.x, mt = blockIdx.y, bl = blockIdx.z;
  int t = threadIdx.x;
  int lane = t & 63, wid = t >> 6;
  int wm = wid & 1, wn = wid >> 1;
  int l16 = lane & 15, quad = lane >> 4;

  const u16* obb = ob + (size_t)bl * N_ * DH_;
  int ra0 = mt * 64 + wm * 32 + l16, ra1 = ra0 + 16;
  int n0g = nt * 64 + wn * 32 + l16;
  int rb0 = n0g < N_ ? n0g : N_ - 1;
  int rb1 = (n0g + 16) < N_ ? n0g + 16 : N_ - 1;

  f32x4 acc[2][2] = {};
  for (int kc = 0; kc < DH_ / 32; ++kc) {
    int k0 = kc * 32 + quad * 8;
    s16x8 a0 = *(const s16x8*)&wpb[(size_t)ra0 * DH_ + k0];
    s16x8 a1 = *(const s16x8*)&wpb[(size_t)ra1 * DH_ + k0];
    s16x8 b0 = *(const s16x8*)&obb[(size_t)rb0 * DH_ + k0];
    s16x8 b1 = *(const s16x8*)&obb[(size_t)rb1 * DH_ + k0];
    acc[0][0] = __builtin_amdgcn_mfma_f32_16x16x32_bf16(a0, b0, acc[0][0], 0, 0, 0);
    acc[0][1] = __builtin_amdgcn_mfma_f32_16x16x32_bf16(a0, b1, acc[0][1], 0, 0, 0);
    acc[1][0] = __builtin_amdgcn_mfma_f32_16x16x32_bf16(a1, b0, acc[1][0], 0, 0, 0);
    acc[1][1] = __builtin_amdgcn_mfma_f32_16x16x32_bf16(a1, b1, acc[1][1], 0, 0, 0);
  }
  for (int mi = 0; mi < 2; ++mi)
    for (int ni = 0; ni < 2; ++ni) {
      int row0 = wm * 32 + mi * 16 + quad * 4;
      int n = nt * 64 + wn * 32 + ni * 16 + l16;
      if (n >= N_) continue;
      int oc0 = mt * 64 + row0;
      float4 bb = *(const float4*)&bp[oc0];
      float4 ss = *(const float4*)&sp[oc0];
      float4 tt = *(const float4*)&tp[oc0];
      float* o = out + ((size_t)(b0 + bl) * DIM_) * N_ + n;
      o[(size_t)(oc0 + 0) * N_] = (acc[mi][ni][0] + bb.x) * ss.x + tt.x;
      o[(size_t)(oc0 + 1) * N_] = (acc[mi][ni][1] + bb.y) * ss.y + tt.y;
      o[(size_t)(oc0 + 2) * N_] = (acc[mi][ni][2] + bb.z) * ss.z + tt.z;
      o[(size_t)(oc0 + 3) * N_] = (acc[mi][ni][3] + bb.w) * ss.w + tt.w;
    }
}

extern "C" void kernel_launch(void* const* d_in, const int* in_sizes, int n_in,
                              void* d_out, int out_size, void* d_ws, size_t ws_size,
                              hipStream_t stream) {
  (void)in_sizes; (void)n_in; (void)out_size;
  const float* x    = (const float*)d_in[0];
  const float* Wq   = (const float*)d_in[1];
  const float* bq   = (const float*)d_in[2];
  const float* sq   = (const float*)d_in[3];
  const float* tq   = (const float*)d_in[4];
  const float* Wk   = (const float*)d_in[5];
  const float* bk   = (const float*)d_in[6];
  const float* sk   = (const float*)d_in[7];
  const float* tk   = (const float*)d_in[8];
  const float* Wv   = (const float*)d_in[9];
  const float* bv   = (const float*)d_in[10];
  const float* sv   = (const float*)d_in[11];
  const float* tv   = (const float*)d_in[12];
  const float* Wvl  = (const float*)d_in[13];
  const float* bvl  = (const float*)d_in[14];
  const float* svl  = (const float*)d_in[15];
  const float* tvl  = (const float*)d_in[16];
  const float* th1w = (const float*)d_in[17];
  const float* th1b = (const float*)d_in[18];
  const float* th2w = (const float*)d_in[19];
  const float* th2b = (const float*)d_in[20];
  const float* ab   = (const float*)d_in[21];
  const float* Wp   = (const float*)d_in[22];
  const float* bp   = (const float*)d_in[23];
  const float* sp   = (const float*)d_in[24];
  const float* tp   = (const float*)d_in[25];
  float* out = (float*)d_out;

  char* ws = (char*)d_ws;
  size_t off = 0;
  auto alloc = [&](size_t bytes) -> void* {
    void* p = ws + off;
    off += (bytes + 255) & ~(size_t)255;
    return p;
  };

  // fixed: bf16 weight copies for the MFMA operands
  u16* wqb = (u16*)alloc((size_t)256 * DIM_ * 2);
  u16* wkb = (u16*)alloc((size_t)256 * DIM_ * 2);
  u16* wvb = (u16*)alloc((size_t)DH_ * DIM_ * 2);
  u16* wpb = (u16*)alloc((size_t)DIM_ * DH_ * 2);
  size_t fixed = off;

  auto footprint = [fixed](int G, int NC) -> size_t {
    auto al = [](size_t b) { return (b + 255) & ~(size_t)255; };
    size_t a = fixed;
    a += al((size_t)G * H_ * N_ * KD_ * 2);   // qb
    a += al((size_t)G * H_ * N_ * KD_ * 2);   // kb
    a += al((size_t)G * DH_ * N_ * 2);        // vb
    a += al((size_t)G * DH_ * N_ * 2);        // vlb
    a += al((size_t)G * N_ * DH_ * 2);        // obb
    size_t xtb = (size_t)G * N_ * DIM_ * 2;
    size_t sb = (size_t)G * H_ * NC * N_ * 4; // Sf (f32), aliases xT
    a += al(sb > xtb ? sb : xtb);
    a += al((size_t)G * H_ * NC * N_ * 2);    // P (bf16 probs)
    return a;
  };
  const int Gs[6] = {32, 16, 8, 4, 2, 1};
  const int NCs[6] = {784, 392, 196, 112, 56, 28};
  int G = 1, NC = 28;
  bool found = false;
  for (int gi = 0; gi < 6 && !found; ++gi)
    for (int ci = 0; ci < 6 && !found; ++ci)
      if (footprint(Gs[gi], NCs[ci]) <= ws_size) { G = Gs[gi]; NC = NCs[ci]; found = true; }

  u16* qb  = (u16*)alloc((size_t)G * H_ * N_ * KD_ * 2);
  u16* kb  = (u16*)alloc((size_t)G * H_ * N_ * KD_ * 2);
  u16* vb  = (u16*)alloc((size_t)G * DH_ * N_ * 2);
  u16* vlb = (u16*)alloc((size_t)G * DH_ * N_ * 2);   // [bl][ch][n]
  u16* obb = (u16*)alloc((size_t)G * N_ * DH_ * 2);
  size_t xtb = (size_t)G * N_ * DIM_ * 2;
  size_t sb = (size_t)G * H_ * NC * N_ * 4;
  float* Sf = (float*)alloc(sb > xtb ? sb : xtb);
  u16* xT = (u16*)Sf;  // xT dead before Sf is first written
  u16* P  = (u16*)alloc((size_t)G * H_ * NC * N_ * 2);

  CvtTab ct;
  ct.src[0] = Wq; ct.dst[0] = wqb; ct.n[0] = 256 * DIM_;
  ct.src[1] = Wk; ct.dst[1] = wkb; ct.n[1] = 256 * DIM_;
  ct.src[2] = Wv; ct.dst[2] = wvb; ct.n[2] = DH_ * DIM_;
  ct.src[3] = Wp; ct.dst[3] = wpb; ct.n[3] = DIM_ * DH_;
  hipLaunchKernelGGL(k_cvt, dim3(96, 4), dim3(256), 0, stream, ct);

  int nchunks = N_ / NC;
  int cn = (NC + 63) / 64;
  for (int b0 = 0; b0 < B_; b0 += G) {
    hipLaunchKernelGGL(k_transpose, dim3(13, 6, G), dim3(256), 0, stream, x, xT, b0);
    hipLaunchKernelGGL(k_proj, dim3(13, 24, G), dim3(256), 0, stream, xT,
                       wqb, wkb, wvb, bq, sq, tq, bk, sk, tk, bv, sv, tv, qb, kb, vb);
    hipLaunchKernelGGL(k_dwconv, dim3(DH_ / 4, G), dim3(256), 0, stream,
                       vb, Wvl, bvl, svl, tvl, vlb);
    for (int c = 0; c < nchunks; ++c) {
      int n0 = c * NC;
      hipLaunchKernelGGL(k_scores, dim3(13, cn, H_), dim3(256), 0, stream,
                         qb, kb, ab, Sf, n0, NC, G);
      hipLaunchKernelGGL(k_softmax, dim3(NC, G), dim3(256), 0, stream,
                         Sf, P, th1w, th1b, th2w, th2b, NC);
      hipLaunchKernelGGL(k_pv, dim3(cn, 2, G * H_), dim3(256), 0, stream,
                         P, vb, vlb, obb, n0, NC);
    }
    hipLaunchKernelGGL(k_outproj, dim3(13, 6, G), dim3(256), 0, stream,
                       obb, wpb, bp, sp, tp, out, b0);
  }
}

// Round 7
// 1329.007 us; speedup vs baseline: 2.7701x; 1.2866x over previous
//
#include <hip/hip_runtime.h>
#include <hip/hip_bf16.h>

#define B_ 32
#define DIM_ 384
#define R_ 28
#define N_ 784
#define H_ 8
#define KD_ 32
#define D_ 128
#define DH_ 1024
#define SCALE_ 0.17677669529663687f

typedef unsigned short u16;
typedef __attribute__((ext_vector_type(4))) float f32x4;
typedef __attribute__((ext_vector_type(8))) short s16x8;

__device__ __forceinline__ float b2f(u16 b) {
  union { unsigned int u; float f; } v; v.u = ((unsigned int)b) << 16; return v.f;
}
__device__ __forceinline__ u16 f2b(float f) {
  union { float f; unsigned int u; } v; v.f = f;
  unsigned int r = v.u + 0x7fffu + ((v.u >> 16) & 1u);
  return (u16)(r >> 16);
}
// y = m / 28 for m < 65536 (magic: 2341 = ceil(2^16/28))
__device__ __forceinline__ int div28(int m) { return (m * 2341) >> 16; }

// ---------------- weight convert f32 -> bf16 (4 arrays) ----------------
struct CvtTab { const float* src[4]; u16* dst[4]; int n[4]; };

__global__ __launch_bounds__(256) void k_cvt(CvtTab tab) {
  int a = blockIdx.y;
  int n4 = tab.n[a] >> 2;
  const float4* s = (const float4*)tab.src[a];
  ushort4* d = (ushort4*)tab.dst[a];
  for (int i = blockIdx.x * 256 + threadIdx.x; i < n4; i += gridDim.x * 256) {
    float4 v = s[i];
    ushort4 o;
    o.x = f2b(v.x); o.y = f2b(v.y); o.z = f2b(v.z); o.w = f2b(v.w);
    d[i] = o;
  }
}

// ---------------- K0: transpose x(f32) [b][c][n] -> xT(bf16) [bl][n][c] ----------------
__global__ __launch_bounds__(256) void k_transpose(const float* __restrict__ x,
                                                   u16* __restrict__ xT, int b0) {
  __shared__ u16 tile[64][65];
  int nt = blockIdx.x, ct = blockIdx.y, bl = blockIdx.z;
  int t = threadIdx.x;
  int n0 = nt * 64, c0 = ct * 64;
  const float* xb = x + (size_t)(b0 + bl) * DIM_ * N_;
  int nl = t & 63, cg = t >> 6;
  for (int i = 0; i < 16; ++i) {
    int cl = cg * 16 + i;
    int n = n0 + nl;
    u16 val = 0;
    if (n < N_) val = f2b(xb[(size_t)(c0 + cl) * N_ + n]);
    tile[cl][nl] = val;
  }
  __syncthreads();
  u16* xTb = xT + (size_t)bl * N_ * DIM_;
  int cl = t & 63, ng = t >> 6;
  for (int i = 0; i < 16; ++i) {
    int n2 = n0 + ng * 16 + i;
    if (n2 < N_) xTb[(size_t)n2 * DIM_ + (c0 + cl)] = tile[cl][ng * 16 + i];
  }
}

// ---------------- K1: QKV projection, 128x128 block / 64x64 wave ----------------
__global__ __launch_bounds__(256) void k_proj(
    const u16* __restrict__ xT,
    const u16* __restrict__ wqb, const u16* __restrict__ wkb, const u16* __restrict__ wvb,
    const float* __restrict__ bq, const float* __restrict__ sq, const float* __restrict__ tq,
    const float* __restrict__ bk, const float* __restrict__ sk, const float* __restrict__ tk,
    const float* __restrict__ bv, const float* __restrict__ sv, const float* __restrict__ tv,
    u16* __restrict__ qb, u16* __restrict__ kb, u16* __restrict__ vb) {
  int nt = blockIdx.x, mt = blockIdx.y, bl = blockIdx.z;
  int t = threadIdx.x;
  int oc0 = mt * 128;
  const u16* Wsrc; const float *bsrc, *ssrc, *tsrc; int obase;
  if (mt < 2)      { Wsrc = wqb; bsrc = bq; ssrc = sq; tsrc = tq; obase = oc0; }
  else if (mt < 4) { Wsrc = wkb; bsrc = bk; ssrc = sk; tsrc = tk; obase = oc0 - 256; }
  else             { Wsrc = wvb; bsrc = bv; ssrc = sv; tsrc = tv; obase = oc0 - 512; }

  int lane = t & 63, wid = t >> 6;
  int wm = wid & 1, wn = wid >> 1;
  int l16 = lane & 15, quad = lane >> 4;

  const u16* xTb = xT + (size_t)bl * N_ * DIM_;
  int ar[4], br[4];
  for (int mi = 0; mi < 4; ++mi) ar[mi] = obase + wm * 64 + mi * 16 + l16;
  for (int ni = 0; ni < 4; ++ni) {
    int n = nt * 128 + wn * 64 + ni * 16 + l16;
    br[ni] = n < N_ ? n : N_ - 1;
  }

  f32x4 acc[4][4] = {};
  #pragma unroll 2
  for (int kc = 0; kc < DIM_ / 32; ++kc) {
    int k0 = kc * 32 + quad * 8;
    s16x8 a[4], b[4];
    for (int mi = 0; mi < 4; ++mi) a[mi] = *(const s16x8*)&Wsrc[(size_t)ar[mi] * DIM_ + k0];
    for (int ni = 0; ni < 4; ++ni) b[ni] = *(const s16x8*)&xTb[(size_t)br[ni] * DIM_ + k0];
    for (int mi = 0; mi < 4; ++mi)
      for (int ni = 0; ni < 4; ++ni)
        acc[mi][ni] = __builtin_amdgcn_mfma_f32_16x16x32_bf16(a[mi], b[ni], acc[mi][ni], 0, 0, 0);
  }
  for (int mi = 0; mi < 4; ++mi)
    for (int ni = 0; ni < 4; ++ni) {
      int row0 = wm * 64 + mi * 16 + quad * 4;
      int col = nt * 128 + wn * 64 + ni * 16 + l16;
      if (col >= N_) continue;
      int ol0 = obase + row0;
      float4 bb = *(const float4*)&bsrc[ol0];
      float4 ss = *(const float4*)&ssrc[ol0];
      float4 tt = *(const float4*)&tsrc[ol0];
      float v0 = (acc[mi][ni][0] + bb.x) * ss.x + tt.x;
      float v1 = (acc[mi][ni][1] + bb.y) * ss.y + tt.y;
      float v2 = (acc[mi][ni][2] + bb.z) * ss.z + tt.z;
      float v3 = (acc[mi][ni][3] + bb.w) * ss.w + tt.w;
      int oc = oc0 + row0;
      if (oc < 512) {
        int h = (oc & 255) >> 5, c0 = oc & 31;
        u16* dst = (oc < 256) ? qb : kb;
        ushort4 o;
        o.x = f2b(v0); o.y = f2b(v1); o.z = f2b(v2); o.w = f2b(v3);
        *(ushort4*)&dst[(((size_t)bl * H_ + h) * N_ + col) * KD_ + c0] = o;
      } else {
        int ch = oc - 512;
        vb[((size_t)bl * DH_ + ch) * N_ + col] = f2b(v0);
        vb[((size_t)bl * DH_ + ch + 1) * N_ + col] = f2b(v1);
        vb[((size_t)bl * DH_ + ch + 2) * N_ + col] = f2b(v2);
        vb[((size_t)bl * DH_ + ch + 3) * N_ + col] = f2b(v3);
      }
    }
}

// ---------------- K2: depthwise 3x3 conv + affine; wave-per-channel ----------------
__global__ __launch_bounds__(256) void k_dwconv(
    const u16* __restrict__ vb, const float* __restrict__ Wvl,
    const float* __restrict__ bvl, const float* __restrict__ svl, const float* __restrict__ tvl,
    u16* __restrict__ vlb) {
  __shared__ u16 img[4][N_];
  int cg = blockIdx.x, bl = blockIdx.y;
  int t = threadIdx.x;
  int wid = t >> 6, lane = t & 63;
  int ch = cg * 4 + wid;
  const u16* vp = vb + ((size_t)bl * DH_ + ch) * N_;
  for (int i = lane; i < N_; i += 64) img[wid][i] = vp[i];
  __syncthreads();
  float w[9];
  for (int i = 0; i < 9; ++i) w[i] = Wvl[ch * 9 + i];
  float bias = bvl[ch], sc = svl[ch], sh = tvl[ch];
  u16* op = vlb + ((size_t)bl * DH_ + ch) * N_;
  for (int p = lane; p < N_; p += 64) {
    int y = p / R_, x = p - y * R_;
    float acc = 0.f;
    #pragma unroll
    for (int dy = -1; dy <= 1; ++dy) {
      int yy = y + dy;
      if (yy < 0 || yy >= R_) continue;
      #pragma unroll
      for (int dx = -1; dx <= 1; ++dx) {
        int xx = x + dx;
        if (xx < 0 || xx >= R_) continue;
        acc += b2f(img[wid][yy * R_ + xx]) * w[(dy + 1) * 3 + (dx + 1)];
      }
    }
    op[p] = f2b((acc + bias) * sc + sh);
  }
}

// ---------------- K3: raw scores (f32), 128x128 tiles, bias via magic-div ----------------
// A = keys (rows m), B = queries (rows n). acc row=m (f32x4 contiguous), col=n.
__global__ __launch_bounds__(256) void k_scores(
    const u16* __restrict__ qb, const u16* __restrict__ kb, const float* __restrict__ ab,
    float* __restrict__ Sf, int n0, int NC, int G) {
  __shared__ float abrow[N_];
  int mt = blockIdx.x, ntl = blockIdx.y, z = blockIdx.z;
  int bl = z >> 3, h = z & 7;
  int t = threadIdx.x;
  const float* abh = ab + (size_t)h * N_;
  for (int i = t; i < N_; i += 256) abrow[i] = abh[i];
  __syncthreads();

  int lane = t & 63, wid = t >> 6;
  int wm = wid & 1, wn = wid >> 1;
  int l16 = lane & 15, quad = lane >> 4;
  int koff = quad * 8;

  size_t hb = ((size_t)bl * H_ + h) * N_;
  int ar[4], br[4], ncol[4], yn[4], xn[4];
  for (int mi = 0; mi < 4; ++mi) {
    int m = mt * 128 + wm * 64 + mi * 16 + l16;
    ar[mi] = m < N_ ? m : N_ - 1;
  }
  for (int ni = 0; ni < 4; ++ni) {
    int nloc = ntl * 128 + wn * 64 + ni * 16 + l16;
    int n_g = n0 + nloc;
    ncol[ni] = nloc;
    int ng = n_g < N_ ? n_g : N_ - 1;
    yn[ni] = div28(ng); xn[ni] = ng - yn[ni] * R_;
    br[ni] = ng;
  }

  s16x8 a[4], b[4];
  for (int mi = 0; mi < 4; ++mi) a[mi] = *(const s16x8*)&kb[(hb + ar[mi]) * KD_ + koff];
  for (int ni = 0; ni < 4; ++ni) b[ni] = *(const s16x8*)&qb[(hb + br[ni]) * KD_ + koff];
  f32x4 acc[4][4] = {};
  for (int mi = 0; mi < 4; ++mi)
    for (int ni = 0; ni < 4; ++ni)
      acc[mi][ni] = __builtin_amdgcn_mfma_f32_16x16x32_bf16(a[mi], b[ni], acc[mi][ni], 0, 0, 0);

  for (int mi = 0; mi < 4; ++mi) {
    int m0 = mt * 128 + wm * 64 + mi * 16 + quad * 4;
    if (m0 >= N_) continue;
    int ym[4], xm[4];
    for (int r = 0; r < 4; ++r) {
      int m = m0 + r;
      ym[r] = div28(m); xm[r] = m - ym[r] * R_;
    }
    for (int ni = 0; ni < 4; ++ni) {
      int nloc = ncol[ni];
      if (nloc >= NC || (n0 + nloc) >= N_) continue;
      f32x4 sv;
      for (int r = 0; r < 4; ++r) {
        int dy = yn[ni] - ym[r]; if (dy < 0) dy = -dy;
        int dx = xn[ni] - xm[r]; if (dx < 0) dx = -dx;
        sv[r] = acc[mi][ni][r] * SCALE_ + abrow[dy * R_ + dx];
      }
      *(f32x4*)&Sf[(((size_t)bl * H_ + h) * NC + nloc) * N_ + m0] = sv;
    }
  }
}

// ---------------- K4: th1-mix + softmax + th2-mix; float4 vectorized ----------------
__global__ __launch_bounds__(256) void k_softmax(
    const float* __restrict__ Sf, u16* __restrict__ P,
    const float* __restrict__ th1w, const float* __restrict__ th1b,
    const float* __restrict__ th2w, const float* __restrict__ th2b, int NC) {
  __shared__ float sm[H_][N_];
  __shared__ float w1[64], bb1[8], w2[64], bb2[8], linv[8];
  int ncl = blockIdx.x, bl = blockIdx.y;
  int t = threadIdx.x;
  if (t < 64) { w1[t] = th1w[t]; w2[t] = th2w[t]; }
  if (t < 8)  { bb1[t] = th1b[t]; bb2[t] = th2b[t]; }
  __syncthreads();
  size_t base = ((size_t)bl * H_ * NC + ncl) * N_;
  size_t hstr = (size_t)NC * N_;
  if (t < 196) {
    int m0 = t * 4;
    f32x4 s[8];
    for (int h = 0; h < 8; ++h) s[h] = *(const f32x4*)&Sf[base + h * hstr + m0];
    for (int g = 0; g < 8; ++g) {
      f32x4 acc = {bb1[g], bb1[g], bb1[g], bb1[g]};
      for (int h = 0; h < 8; ++h) {
        float w = w1[g * 8 + h];
        acc[0] += w * s[h][0]; acc[1] += w * s[h][1];
        acc[2] += w * s[h][2]; acc[3] += w * s[h][3];
      }
      *(f32x4*)&sm[g][m0] = acc;
    }
  }
  __syncthreads();
  int lane = t & 63, wid = t >> 6;
  for (int gi = 0; gi < 2; ++gi) {
    int g = wid + gi * 4;
    float mx = -1e30f;
    for (int m = lane; m < N_; m += 64) mx = fmaxf(mx, sm[g][m]);
    for (int off = 32; off >= 1; off >>= 1) mx = fmaxf(mx, __shfl_xor(mx, off));
    float sum = 0.f;
    for (int m = lane; m < N_; m += 64) {
      float e = __expf(sm[g][m] - mx);
      sm[g][m] = e;
      sum += e;
    }
    for (int off = 32; off >= 1; off >>= 1) sum += __shfl_xor(sum, off);
    if (lane == 0) linv[g] = 1.f / sum;
  }
  __syncthreads();
  if (t < 196) {
    int m0 = t * 4;
    float li[8];
    for (int g = 0; g < 8; ++g) li[g] = linv[g];
    f32x4 p[8];
    for (int g = 0; g < 8; ++g) {
      p[g] = *(const f32x4*)&sm[g][m0];
      p[g][0] *= li[g]; p[g][1] *= li[g]; p[g][2] *= li[g]; p[g][3] *= li[g];
    }
    for (int f = 0; f < 8; ++f) {
      f32x4 acc = {bb2[f], bb2[f], bb2[f], bb2[f]};
      for (int g = 0; g < 8; ++g) {
        float w = w2[f * 8 + g];
        acc[0] += w * p[g][0]; acc[1] += w * p[g][1];
        acc[2] += w * p[g][2]; acc[3] += w * p[g][3];
      }
      ushort4 o;
      o.x = f2b(acc[0]); o.y = f2b(acc[1]); o.z = f2b(acc[2]); o.w = f2b(acc[3]);
      *(ushort4*)&P[base + f * hstr + m0] = o;
    }
  }
}

// ---------------- K5: O' = relu(attn @ V + vl), 128x128 tiles ----------------
// A = V (rows d=128), B = P (rows n). acc row=d, col=n.
__global__ __launch_bounds__(256) void k_pv(
    const u16* __restrict__ P, const u16* __restrict__ vb, const u16* __restrict__ vlb,
    u16* __restrict__ ob, int n0, int NC) {
  int ntl = blockIdx.x, z = blockIdx.z;
  int bl = z >> 3, f = z & 7;
  int t = threadIdx.x;
  int lane = t & 63, wid = t >> 6;
  int wm = wid & 1, wn = wid >> 1;
  int l16 = lane & 15, quad = lane >> 4;

  const u16* vsrc = vb + ((size_t)bl * DH_ + f * D_) * N_;
  const u16* asrc = P + ((size_t)bl * H_ + f) * (size_t)NC * N_;

  int da[4], br[4];
  for (int mi = 0; mi < 4; ++mi) da[mi] = wm * 64 + mi * 16 + l16;
  for (int ni = 0; ni < 4; ++ni) {
    int nl = ntl * 128 + wn * 64 + ni * 16 + l16;
    br[ni] = nl < NC ? nl : NC - 1;
  }

  f32x4 acc[4][4] = {};
  #pragma unroll 2
  for (int kc = 0; kc < 25; ++kc) {
    int kk = kc * 32 + quad * 8;
    s16x8 a[4] = {}, b[4] = {};
    if (kk + 8 <= N_) {
      for (int mi = 0; mi < 4; ++mi) a[mi] = *(const s16x8*)&vsrc[(size_t)da[mi] * N_ + kk];
      for (int ni = 0; ni < 4; ++ni) b[ni] = *(const s16x8*)&asrc[(size_t)br[ni] * N_ + kk];
    }
    for (int mi = 0; mi < 4; ++mi)
      for (int ni = 0; ni < 4; ++ni)
        acc[mi][ni] = __builtin_amdgcn_mfma_f32_16x16x32_bf16(a[mi], b[ni], acc[mi][ni], 0, 0, 0);
  }
  for (int mi = 0; mi < 4; ++mi)
    for (int ni = 0; ni < 4; ++ni) {
      int row = wm * 64 + mi * 16 + quad * 4;
      int col = wn * 64 + ni * 16 + l16;
      int nloc = ntl * 128 + col;
      if (nloc >= NC || (n0 + nloc) >= N_) continue;
      int ch = f * D_ + row;
      size_t vaddr = ((size_t)bl * DH_ + ch) * N_ + (n0 + nloc);
      float o0 = acc[mi][ni][0] + b2f(vlb[vaddr]);
      float o1 = acc[mi][ni][1] + b2f(vlb[vaddr + N_]);
      float o2 = acc[mi][ni][2] + b2f(vlb[vaddr + 2 * N_]);
      float o3 = acc[mi][ni][3] + b2f(vlb[vaddr + 3 * N_]);
      size_t addr = ((size_t)bl * N_ + (n0 + nloc)) * DH_ + ch;
      ushort4 o4;
      o4.x = f2b(o0 > 0.f ? o0 : 0.f);
      o4.y = f2b(o1 > 0.f ? o1 : 0.f);
      o4.z = f2b(o2 > 0.f ? o2 : 0.f);
      o4.w = f2b(o3 > 0.f ? o3 : 0.f);
      *(ushort4*)&ob[addr] = o4;
    }
}

// ---------------- K6: out = affine(Wp @ O' + bp), 128x128 tiles, f32 out ----------------
__global__ __launch_bounds__(256) void k_outproj(
    const u16* __restrict__ ob, const u16* __restrict__ wpb,
    const float* __restrict__ bp, const float* __restrict__ sp, const float* __restrict__ tp,
    float* __restrict__ out, int b0) {
  int nt = blockIdx.x, mt = blockIdx.y, bl = blockIdx.z;
  int t = threadIdx.x;
  int lane = t & 63, wid = t >> 6;
  int wm = wid & 1, wn = wid >> 1;
  int l16 = lane & 15, quad = lane >> 4;

  const u16* obb = ob + (size_t)bl * N_ * DH_;
  int ar[4], br[4];
  for (int mi = 0; mi < 4; ++mi) ar[mi] = mt * 128 + wm * 64 + mi * 16 + l16;
  for (int ni = 0; ni < 4; ++ni) {
    int n = nt * 128 + wn * 64 + ni * 16 + l16;
    br[ni] = n < N_ ? n : N_ - 1;
  }

  f32x4 acc[4][4] = {};
  #pragma unroll 2
  for (int kc = 0; kc < DH_ / 32; ++kc) {
    int k0 = kc * 32 + quad * 8;
    s16x8 a[4], b[4];
    for (int mi = 0; mi < 4; ++mi) a[mi] = *(const s16x8*)&wpb[(size_t)ar[mi] * DH_ + k0];
    for (int ni = 0; ni < 4; ++ni) b[ni] = *(const s16x8*)&obb[(size_t)br[ni] * DH_ + k0];
    for (int mi = 0; mi < 4; ++mi)
      for (int ni = 0; ni < 4; ++ni)
        acc[mi][ni] = __builtin_amdgcn_mfma_f32_16x16x32_bf16(a[mi], b[ni], acc[mi][ni], 0, 0, 0);
  }
  for (int mi = 0; mi < 4; ++mi)
    for (int ni = 0; ni < 4; ++ni) {
      int row0 = wm * 64 + mi * 16 + quad * 4;
      int n = nt * 128 + wn * 64 + ni * 16 + l16;
      if (n >= N_) continue;
      int oc0 = mt * 128 + row0;
      float4 bb = *(const float4*)&bp[oc0];
      float4 ss = *(const float4*)&sp[oc0];
      float4 tt = *(const float4*)&tp[oc0];
      float* o = out + ((size_t)(b0 + bl) * DIM_) * N_ + n;
      o[(size_t)(oc0 + 0) * N_] = (acc[mi][ni][0] + bb.x) * ss.x + tt.x;
      o[(size_t)(oc0 + 1) * N_] = (acc[mi][ni][1] + bb.y) * ss.y + tt.y;
      o[(size_t)(oc0 + 2) * N_] = (acc[mi][ni][2] + bb.z) * ss.z + tt.z;
      o[(size_t)(oc0 + 3) * N_] = (acc[mi][ni][3] + bb.w) * ss.w + tt.w;
    }
}

extern "C" void kernel_launch(void* const* d_in, const int* in_sizes, int n_in,
                              void* d_out, int out_size, void* d_ws, size_t ws_size,
                              hipStream_t stream) {
  (void)in_sizes; (void)n_in; (void)out_size;
  const float* x    = (const float*)d_in[0];
  const float* Wq   = (const float*)d_in[1];
  const float* bq   = (const float*)d_in[2];
  const float* sq   = (const float*)d_in[3];
  const float* tq   = (const float*)d_in[4];
  const float* Wk   = (const float*)d_in[5];
  const float* bk   = (const float*)d_in[6];
  const float* sk   = (const float*)d_in[7];
  const float* tk   = (const float*)d_in[8];
  const float* Wv   = (const float*)d_in[9];
  const float* bv   = (const float*)d_in[10];
  const float* sv   = (const float*)d_in[11];
  const float* tv   = (const float*)d_in[12];
  const float* Wvl  = (const float*)d_in[13];
  const float* bvl  = (const float*)d_in[14];
  const float* svl  = (const float*)d_in[15];
  const float* tvl  = (const float*)d_in[16];
  const float* th1w = (const float*)d_in[17];
  const float* th1b = (const float*)d_in[18];
  const float* th2w = (const float*)d_in[19];
  const float* th2b = (const float*)d_in[20];
  const float* ab   = (const float*)d_in[21];
  const float* Wp   = (const float*)d_in[22];
  const float* bp   = (const float*)d_in[23];
  const float* sp   = (const float*)d_in[24];
  const float* tp   = (const float*)d_in[25];
  float* out = (float*)d_out;

  char* ws = (char*)d_ws;
  size_t off = 0;
  auto alloc = [&](size_t bytes) -> void* {
    void* p = ws + off;
    off += (bytes + 255) & ~(size_t)255;
    return p;
  };

  u16* wqb = (u16*)alloc((size_t)256 * DIM_ * 2);
  u16* wkb = (u16*)alloc((size_t)256 * DIM_ * 2);
  u16* wvb = (u16*)alloc((size_t)DH_ * DIM_ * 2);
  u16* wpb = (u16*)alloc((size_t)DIM_ * DH_ * 2);
  size_t fixed = off;

  auto footprint = [fixed](int G, int NC) -> size_t {
    auto al = [](size_t b) { return (b + 255) & ~(size_t)255; };
    size_t a = fixed;
    a += al((size_t)G * H_ * N_ * KD_ * 2);   // qb
    a += al((size_t)G * H_ * N_ * KD_ * 2);   // kb
    a += al((size_t)G * DH_ * N_ * 2);        // vb
    a += al((size_t)G * DH_ * N_ * 2);        // vlb
    a += al((size_t)G * N_ * DH_ * 2);        // obb
    size_t xtb = (size_t)G * N_ * DIM_ * 2;
    size_t sb = (size_t)G * H_ * NC * N_ * 4; // Sf (f32), aliases xT
    a += al(sb > xtb ? sb : xtb);
    a += al((size_t)G * H_ * NC * N_ * 2);    // P (bf16 probs)
    return a;
  };
  const int Gs[6] = {32, 16, 8, 4, 2, 1};
  const int NCs[6] = {784, 392, 196, 112, 56, 28};
  int G = 1, NC = 28;
  bool found = false;
  for (int gi = 0; gi < 6 && !found; ++gi)
    for (int ci = 0; ci < 6 && !found; ++ci)
      if (footprint(Gs[gi], NCs[ci]) <= ws_size) { G = Gs[gi]; NC = NCs[ci]; found = true; }

  u16* qb  = (u16*)alloc((size_t)G * H_ * N_ * KD_ * 2);
  u16* kb  = (u16*)alloc((size_t)G * H_ * N_ * KD_ * 2);
  u16* vb  = (u16*)alloc((size_t)G * DH_ * N_ * 2);
  u16* vlb = (u16*)alloc((size_t)G * DH_ * N_ * 2);   // [bl][ch][n]
  u16* obb = (u16*)alloc((size_t)G * N_ * DH_ * 2);
  size_t xtb = (size_t)G * N_ * DIM_ * 2;
  size_t sb = (size_t)G * H_ * NC * N_ * 4;
  float* Sf = (float*)alloc(sb > xtb ? sb : xtb);
  u16* xT = (u16*)Sf;  // xT dead before Sf is first written
  u16* P  = (u16*)alloc((size_t)G * H_ * NC * N_ * 2);

  CvtTab ct;
  ct.src[0] = Wq; ct.dst[0] = wqb; ct.n[0] = 256 * DIM_;
  ct.src[1] = Wk; ct.dst[1] = wkb; ct.n[1] = 256 * DIM_;
  ct.src[2] = Wv; ct.dst[2] = wvb; ct.n[2] = DH_ * DIM_;
  ct.src[3] = Wp; ct.dst[3] = wpb; ct.n[3] = DIM_ * DH_;
  hipLaunchKernelGGL(k_cvt, dim3(96, 4), dim3(256), 0, stream, ct);

  int nchunks = N_ / NC;
  int cn128 = (NC + 127) / 128;
  for (int b0 = 0; b0 < B_; b0 += G) {
    hipLaunchKernelGGL(k_transpose, dim3(13, 6, G), dim3(256), 0, stream, x, xT, b0);
    hipLaunchKernelGGL(k_proj, dim3(7, 12, G), dim3(256), 0, stream, xT,
                       wqb, wkb, wvb, bq, sq, tq, bk, sk, tk, bv, sv, tv, qb, kb, vb);
    hipLaunchKernelGGL(k_dwconv, dim3(DH_ / 4, G), dim3(256), 0, stream,
                       vb, Wvl, bvl, svl, tvl, vlb);
    for (int c = 0; c < nchunks; ++c) {
      int n0 = c * NC;
      hipLaunchKernelGGL(k_scores, dim3(7, cn128, G * H_), dim3(256), 0, stream,
                         qb, kb, ab, Sf, n0, NC, G);
      hipLaunchKernelGGL(k_softmax, dim3(NC, G), dim3(256), 0, stream,
                         Sf, P, th1w, th1b, th2w, th2b, NC);
      hipLaunchKernelGGL(k_pv, dim3(cn128, 1, G * H_), dim3(256), 0, stream,
                         P, vb, vlb, obb, n0, NC);
    }
    hipLaunchKernelGGL(k_outproj, dim3(7, 3, G), dim3(256), 0, stream,
                       obb, wpb, bp, sp, tp, out, b0);
  }
}